// Round 3
// baseline (535.363 us; speedup 1.0000x reference)
//
#include <hip/hip_runtime.h>
#include <hip/hip_bf16.h>
#include <stdint.h>

typedef __bf16 bf16_t;
typedef __bf16 bf16x8 __attribute__((ext_vector_type(8)));
typedef __bf16 bf16x4 __attribute__((ext_vector_type(4)));
typedef float f32x4 __attribute__((ext_vector_type(4)));

static constexpr int TT = 2048, CC = 1024;

__device__ __forceinline__ void gld_lds16(const void* g, void* l) {
  __builtin_amdgcn_global_load_lds((const __attribute__((address_space(1))) void*)g,
                                   (__attribute__((address_space(3))) void*)l, 16, 0, 0);
}

// out[n][k] = (bf16) in[k][n]; per-batch stride K*N both sides
__global__ __launch_bounds__(256) void transpose_cvt(const float* __restrict__ in,
                                                     bf16_t* __restrict__ out,
                                                     int K, int N) {
  __shared__ float t[32][33];
  const int k0 = blockIdx.x * 32, n0 = blockIdx.y * 32;
  const size_t boff = (size_t)blockIdx.z * K * N;
  in += boff;
  out += boff;
  const int tx = threadIdx.x & 31, ty = threadIdx.x >> 5;
#pragma unroll
  for (int j = 0; j < 4; ++j)
    t[ty + j * 8][tx] = in[(size_t)(k0 + ty + j * 8) * N + n0 + tx];
  __syncthreads();
#pragma unroll
  for (int j = 0; j < 4; ++j)
    out[(size_t)(n0 + ty + j * 8) * K + k0 + tx] = (bf16_t)t[tx][ty + j * 8];
}

// LayerNorm over C=1024, one block (256 thr) per row, bf16 out
__global__ __launch_bounds__(256) void ln_f32_bf16(const float* __restrict__ x,
                                                   const float* __restrict__ g,
                                                   const float* __restrict__ b,
                                                   bf16_t* __restrict__ out) {
  const int row = blockIdx.x;
  const int tid = threadIdx.x;
  const float4 v = ((const float4*)(x + (size_t)row * CC))[tid];
  float s = v.x + v.y + v.z + v.w;
  float q = v.x * v.x + v.y * v.y + v.z * v.z + v.w * v.w;
#pragma unroll
  for (int off = 1; off < 64; off <<= 1) {
    s += __shfl_xor(s, off);
    q += __shfl_xor(q, off);
  }
  __shared__ float red[8];
  const int wave = tid >> 6, lane = tid & 63;
  if (lane == 0) { red[wave] = s; red[4 + wave] = q; }
  __syncthreads();
  s = red[0] + red[1] + red[2] + red[3];
  q = red[4] + red[5] + red[6] + red[7];
  const float mu = s * (1.0f / CC);
  float var = q * (1.0f / CC) - mu * mu;
  var = fmaxf(var, 0.f);
  const float rstd = rsqrtf(var + 1e-5f);
  const float4 gv = ((const float4*)g)[tid];
  const float4 bv = ((const float4*)b)[tid];
  bf16x4 o;
  o[0] = (bf16_t)((v.x - mu) * rstd * gv.x + bv.x);
  o[1] = (bf16_t)((v.y - mu) * rstd * gv.y + bv.y);
  o[2] = (bf16_t)((v.z - mu) * rstd * gv.z + bv.z);
  o[3] = (bf16_t)((v.w - mu) * rstd * gv.w + bv.w);
  *(bf16x4*)(out + (size_t)row * CC + tid * 4) = o;
}

// C = A[M,K] @ Bt[N,K]^T ; A,Bt bf16 row-major. 128x128 tile, BK=32, 4 waves.
// EPI: 0 = bf16 store; 1 = bf16 store of relu(acc+bias); 2 = f32 store of acc+bias+res
// EPI: 3 = bf16 store, but cols >= 2048 go transposed to vt[bh][d][T] (QKV fused V-transpose)
template <int EPI>
__global__ __launch_bounds__(256) void gemm_bt(const bf16_t* __restrict__ A,
                                               const bf16_t* __restrict__ Bt,
                                               void* __restrict__ Cout,
                                               const float* __restrict__ bias,
                                               const float* __restrict__ res,
                                               bf16_t* __restrict__ vt,
                                               int M, int N, int K) {
  __shared__ alignas(16) bf16_t As[128 * 32];
  __shared__ alignas(16) bf16_t Bs[128 * 32];
  const int tid = threadIdx.x;
  const int wave = tid >> 6, lane = tid & 63;
  const int lr = lane & 15, lg = lane >> 4;
  const int wm = wave >> 1, wn = wave & 1;
  const int tm0 = blockIdx.y * 128, tn0 = blockIdx.x * 128;

  const int r0 = wave * 32 + (lane >> 2);
  const int kc = (lane & 3) * 8;
  const bf16_t* Ag0 = A + (size_t)(tm0 + r0) * K + kc;
  const bf16_t* Ag1 = Ag0 + (size_t)16 * K;
  const bf16_t* Bg0 = Bt + (size_t)(tn0 + r0) * K + kc;
  const bf16_t* Bg1 = Bg0 + (size_t)16 * K;
  bf16_t* Al = As + (size_t)(wave * 2) * 512;
  bf16_t* Bl = Bs + (size_t)(wave * 2) * 512;

  f32x4 acc[4][4] = {};
  for (int k0 = 0; k0 < K; k0 += 32) {
    gld_lds16(Ag0 + k0, Al);
    gld_lds16(Ag1 + k0, Al + 512);
    gld_lds16(Bg0 + k0, Bl);
    gld_lds16(Bg1 + k0, Bl + 512);
    __syncthreads();
    bf16x8 af[4], bfr[4];
#pragma unroll
    for (int m = 0; m < 4; ++m)
      af[m] = *(const bf16x8*)&As[(wm * 64 + m * 16 + lr) * 32 + lg * 8];
#pragma unroll
    for (int n = 0; n < 4; ++n)
      bfr[n] = *(const bf16x8*)&Bs[(wn * 64 + n * 16 + lr) * 32 + lg * 8];
#pragma unroll
    for (int m = 0; m < 4; ++m)
#pragma unroll
      for (int n = 0; n < 4; ++n)
        acc[m][n] = __builtin_amdgcn_mfma_f32_16x16x32_bf16(af[m], bfr[n], acc[m][n], 0, 0, 0);
    __syncthreads();
  }
#pragma unroll
  for (int m = 0; m < 4; ++m) {
#pragma unroll
    for (int i = 0; i < 4; ++i) {
      const int row = tm0 + wm * 64 + m * 16 + lg * 4 + i;
#pragma unroll
      for (int n = 0; n < 4; ++n) {
        const int col = tn0 + wn * 64 + n * 16 + lr;
        float v = acc[m][n][i];
        if (EPI == 1) v = fmaxf(v + bias[col], 0.f);
        if (EPI == 2) v = v + bias[col] + res[(size_t)row * N + col];
        if (EPI == 2) {
          ((float*)Cout)[(size_t)row * N + col] = v;
        } else if (EPI == 3) {
          if (col >= 2048) {
            const int hd = col - 2048;  // h*64 + d
            const size_t vidx =
                ((size_t)((row >> 11) * 16 + (hd >> 6)) * 64 + (hd & 63)) * TT + (row & (TT - 1));
            vt[vidx] = (bf16_t)v;
          } else {
            ((bf16_t*)Cout)[(size_t)row * N + col] = (bf16_t)v;
          }
        } else {
          ((bf16_t*)Cout)[(size_t)row * N + col] = (bf16_t)v;
        }
      }
    }
  }
}

// Flash attention, causal, D=64, T=2048. Barrier-free: 4 independent waves per block,
// each wave owns 16 q-rows. K read from qkv (row-major), V read from Vt[bh][d][t].
// KVBLK=64 per iteration. scale = 1024^-0.5 = 1/32.
__global__ __launch_bounds__(256) void attn_fwd(const bf16_t* __restrict__ qkv,
                                                const bf16_t* __restrict__ Vt,
                                                bf16_t* __restrict__ O) {
  const int bh = blockIdx.y;
  const int bb = bh >> 4, hh = bh & 15;
  const int bx = blockIdx.x;
  const int qt = (bx & 1) ? (31 - (bx >> 1)) : (bx >> 1);  // pair heavy+light tiles
  const int qbase = qt * 64;
  const int tid = threadIdx.x;
  const int wave = tid >> 6, lane = tid & 63;
  const int lr = lane & 15, lg = lane >> 4;
  const bf16_t* Qp = qkv + (size_t)bb * TT * 3072 + hh * 64;
  const bf16_t* Kp = Qp + 1024;
  const bf16_t* Vh = Vt + (size_t)bh * 64 * TT;

  __shared__ alignas(16) bf16_t PlS[4][16][64];  // per-wave P tile, XOR-swizzled cols
  bf16_t* Pw = &PlS[wave][0][0];

  const int qrow = qbase + wave * 16;
  const bf16x8 qf0 = *(const bf16x8*)(Qp + (size_t)(qrow + lr) * 3072 + lg * 8);
  const bf16x8 qf1 = *(const bf16x8*)(Qp + (size_t)(qrow + lr) * 3072 + 32 + lg * 8);

  f32x4 oacc[4] = {};
  float m_r[4], l_r[4];
#pragma unroll
  for (int i = 0; i < 4; ++i) { m_r[i] = -1e38f; l_r[i] = 0.f; }

  const float scale = 0.03125f;

  for (int s0 = 0; s0 < qbase + 64; s0 += 64) {
    // ---- QK^T: 4 chunks of 16 s, k=64 ----
    float P[4][4];
    __builtin_amdgcn_s_setprio(1);
#pragma unroll
    for (int ct = 0; ct < 4; ++ct) {
      const bf16_t* Kr = Kp + (size_t)(s0 + ct * 16 + lr) * 3072;
      const bf16x8 kf0 = *(const bf16x8*)(Kr + lg * 8);
      const bf16x8 kf1 = *(const bf16x8*)(Kr + 32 + lg * 8);
      f32x4 z = {};
      z = __builtin_amdgcn_mfma_f32_16x16x32_bf16(qf0, kf0, z, 0, 0, 0);
      z = __builtin_amdgcn_mfma_f32_16x16x32_bf16(qf1, kf1, z, 0, 0, 0);
      const int sg = s0 + ct * 16 + lr;
#pragma unroll
      for (int i = 0; i < 4; ++i) {
        float sv = z[i] * scale;
        if (sg > qrow + lg * 4 + i) sv = -1e30f;  // causal mask
        P[ct][i] = sv;
      }
    }
    __builtin_amdgcn_s_setprio(0);

    // ---- prefetch V fragments (L2-resident; latency hides under softmax) ----
    bf16x8 vf[2][4];
#pragma unroll
    for (int kc = 0; kc < 2; ++kc)
#pragma unroll
      for (int db = 0; db < 4; ++db)
        vf[kc][db] = *(const bf16x8*)(Vh + (size_t)(db * 16 + lr) * TT + s0 + kc * 32 + lg * 8);

    // ---- online softmax over 64 s ----
    float rm[4], alpha[4], lad[4];
#pragma unroll
    for (int i = 0; i < 4; ++i)
      rm[i] = fmaxf(fmaxf(P[0][i], P[1][i]), fmaxf(P[2][i], P[3][i]));
#pragma unroll
    for (int off = 1; off < 16; off <<= 1)
#pragma unroll
      for (int i = 0; i < 4; ++i) rm[i] = fmaxf(rm[i], __shfl_xor(rm[i], off));
#pragma unroll
    for (int i = 0; i < 4; ++i) {
      const float mn = fmaxf(m_r[i], rm[i]);
      alpha[i] = __expf(m_r[i] - mn);
      m_r[i] = mn;
      float acc_l = 0.f;
#pragma unroll
      for (int ct = 0; ct < 4; ++ct) {
        const float p = __expf(P[ct][i] - mn);
        P[ct][i] = p;
        acc_l += p;
      }
      lad[i] = acc_l;
    }
#pragma unroll
    for (int off = 1; off < 16; off <<= 1)
#pragma unroll
      for (int i = 0; i < 4; ++i) lad[i] += __shfl_xor(lad[i], off);
#pragma unroll
    for (int i = 0; i < 4; ++i) l_r[i] = l_r[i] * alpha[i] + lad[i];

    // ---- P -> LDS (XOR-swizzled), redistribute to A-fragment layout ----
#pragma unroll
    for (int ct = 0; ct < 4; ++ct)
#pragma unroll
      for (int i = 0; i < 4; ++i) {
        const int q = lg * 4 + i;
        const int col = (ct * 16 + lr) ^ ((q & 7) << 3);
        Pw[q * 64 + col] = (bf16_t)P[ct][i];
      }
    asm volatile("s_waitcnt lgkmcnt(0)" ::: "memory");
    __builtin_amdgcn_sched_barrier(0);

    // ---- rescale O, then PV ----
#pragma unroll
    for (int db = 0; db < 4; ++db)
#pragma unroll
      for (int i = 0; i < 4; ++i) oacc[db][i] *= alpha[i];

    __builtin_amdgcn_s_setprio(1);
#pragma unroll
    for (int kc = 0; kc < 2; ++kc) {
      const bf16x8 pf = *(const bf16x8*)&Pw[lr * 64 + ((kc * 32 + lg * 8) ^ ((lr & 7) << 3))];
#pragma unroll
      for (int db = 0; db < 4; ++db)
        oacc[db] = __builtin_amdgcn_mfma_f32_16x16x32_bf16(pf, vf[kc][db], oacc[db], 0, 0, 0);
    }
    __builtin_amdgcn_s_setprio(0);
  }

  bf16_t* Op = O + ((size_t)bb * TT + qrow) * CC + hh * 64;
#pragma unroll
  for (int db = 0; db < 4; ++db)
#pragma unroll
    for (int i = 0; i < 4; ++i)
      Op[(size_t)(lg * 4 + i) * CC + db * 16 + lr] = (bf16_t)(oacc[db][i] / l_r[i]);
}

extern "C" void kernel_launch(void* const* d_in, const int* in_sizes, int n_in,
                              void* d_out, int out_size, void* d_ws, size_t ws_size,
                              hipStream_t stream) {
  const float* x      = (const float*)d_in[0];
  const float* wq     = (const float*)d_in[1];
  const float* wk     = (const float*)d_in[2];
  const float* wv     = (const float*)d_in[3];
  const float* w_proj = (const float*)d_in[4];
  const float* b_proj = (const float*)d_in[5];
  const float* w1     = (const float*)d_in[6];
  const float* b1     = (const float*)d_in[7];
  const float* w2     = (const float*)d_in[8];
  const float* b2     = (const float*)d_in[9];
  const float* ln1_g  = (const float*)d_in[10];
  const float* ln1_b  = (const float*)d_in[11];
  const float* ln2_g  = (const float*)d_in[12];
  const float* ln2_b  = (const float*)d_in[13];

  char* ws = (char*)d_ws;
  const size_t MB = 1024 * 1024;
  bf16_t* h1    = (bf16_t*)(ws + 0);         // 8 MB  [4096][1024]
  bf16_t* Bqkv  = (bf16_t*)(ws + 8 * MB);    // 6 MB  [3072][1024]
  bf16_t* Bproj = (bf16_t*)(ws + 14 * MB);   // 2 MB  [1024][1024]
  bf16_t* B1w   = (bf16_t*)(ws + 16 * MB);   // 8 MB  [4096][1024]
  bf16_t* B2w   = (bf16_t*)(ws + 24 * MB);   // 8 MB  [1024][4096]
  bf16_t* qkv   = (bf16_t*)(ws + 32 * MB);   // 24 MB [4096][3072] (V region unused)
  bf16_t* Obuf  = (bf16_t*)(ws + 56 * MB);   // 8 MB  [4096][1024]
  float*  res1  = (float*)(ws + 64 * MB);    // 16 MB [4096][1024], written AFTER attn
  bf16_t* Vt    = (bf16_t*)(ws + 64 * MB);   // 16 MB [32][64][2048], dead once attn done
  bf16_t* h2    = (bf16_t*)(ws + 80 * MB);   // 8 MB  [4096][1024]
  bf16_t* a1    = (bf16_t*)(ws + 32 * MB);   // 32 MB [4096][4096], reuses qkv+Obuf
  float*  outp  = (float*)d_out;

  dim3 blk(256);
  // weight prep: Bt[n][k] layouts
  transpose_cvt<<<dim3(32, 2, 16), blk, 0, stream>>>(wq, Bqkv, 1024, 64);
  transpose_cvt<<<dim3(32, 2, 16), blk, 0, stream>>>(wk, Bqkv + 1024 * 1024, 1024, 64);
  transpose_cvt<<<dim3(32, 2, 16), blk, 0, stream>>>(wv, Bqkv + 2 * 1024 * 1024, 1024, 64);
  transpose_cvt<<<dim3(32, 32, 1), blk, 0, stream>>>(w_proj, Bproj, 1024, 1024);
  transpose_cvt<<<dim3(32, 128, 1), blk, 0, stream>>>(w1, B1w, 1024, 4096);
  transpose_cvt<<<dim3(128, 32, 1), blk, 0, stream>>>(w2, B2w, 4096, 1024);

  ln_f32_bf16<<<dim3(4096), blk, 0, stream>>>(x, ln1_g, ln1_b, h1);
  gemm_bt<3><<<dim3(24, 32), blk, 0, stream>>>(h1, Bqkv, qkv, nullptr, nullptr, Vt, 4096, 3072, 1024);
  attn_fwd<<<dim3(32, 32), blk, 0, stream>>>(qkv, Vt, Obuf);
  gemm_bt<2><<<dim3(8, 32), blk, 0, stream>>>(Obuf, Bproj, res1, b_proj, x, nullptr, 4096, 1024, 1024);
  ln_f32_bf16<<<dim3(4096), blk, 0, stream>>>(res1, ln2_g, ln2_b, h2);
  gemm_bt<1><<<dim3(32, 32), blk, 0, stream>>>(h2, B1w, a1, b1, nullptr, nullptr, 4096, 4096, 1024);
  gemm_bt<2><<<dim3(8, 32), blk, 0, stream>>>(a1, B2w, outp, b2, res1, nullptr, 4096, 1024, 4096);
}

// Round 4
// 364.314 us; speedup vs baseline: 1.4695x; 1.4695x over previous
//
#include <hip/hip_runtime.h>
#include <hip/hip_bf16.h>
#include <stdint.h>

typedef __bf16 bf16_t;
typedef __bf16 bf16x8 __attribute__((ext_vector_type(8)));
typedef __bf16 bf16x4 __attribute__((ext_vector_type(4)));
typedef float f32x4 __attribute__((ext_vector_type(4)));

static constexpr int TT = 2048, CC = 1024;

__device__ __forceinline__ void gld_lds16(const void* g, void* l) {
  __builtin_amdgcn_global_load_lds((const __attribute__((address_space(1))) void*)g,
                                   (__attribute__((address_space(3))) void*)l, 16, 0, 0);
}

// out[n][k] = (bf16) in[k][n]; per-batch stride K*N both sides
__global__ __launch_bounds__(256) void transpose_cvt(const float* __restrict__ in,
                                                     bf16_t* __restrict__ out,
                                                     int K, int N) {
  __shared__ float t[32][33];
  const int k0 = blockIdx.x * 32, n0 = blockIdx.y * 32;
  const size_t boff = (size_t)blockIdx.z * K * N;
  in += boff;
  out += boff;
  const int tx = threadIdx.x & 31, ty = threadIdx.x >> 5;
#pragma unroll
  for (int j = 0; j < 4; ++j)
    t[ty + j * 8][tx] = in[(size_t)(k0 + ty + j * 8) * N + n0 + tx];
  __syncthreads();
#pragma unroll
  for (int j = 0; j < 4; ++j)
    out[(size_t)(n0 + ty + j * 8) * K + k0 + tx] = (bf16_t)t[tx][ty + j * 8];
}

// LayerNorm over C=1024, one block (256 thr) per row, bf16 out
__global__ __launch_bounds__(256) void ln_f32_bf16(const float* __restrict__ x,
                                                   const float* __restrict__ g,
                                                   const float* __restrict__ b,
                                                   bf16_t* __restrict__ out) {
  const int row = blockIdx.x;
  const int tid = threadIdx.x;
  const float4 v = ((const float4*)(x + (size_t)row * CC))[tid];
  float s = v.x + v.y + v.z + v.w;
  float q = v.x * v.x + v.y * v.y + v.z * v.z + v.w * v.w;
#pragma unroll
  for (int off = 1; off < 64; off <<= 1) {
    s += __shfl_xor(s, off);
    q += __shfl_xor(q, off);
  }
  __shared__ float red[8];
  const int wave = tid >> 6, lane = tid & 63;
  if (lane == 0) { red[wave] = s; red[4 + wave] = q; }
  __syncthreads();
  s = red[0] + red[1] + red[2] + red[3];
  q = red[4] + red[5] + red[6] + red[7];
  const float mu = s * (1.0f / CC);
  float var = q * (1.0f / CC) - mu * mu;
  var = fmaxf(var, 0.f);
  const float rstd = rsqrtf(var + 1e-5f);
  const float4 gv = ((const float4*)g)[tid];
  const float4 bv = ((const float4*)b)[tid];
  bf16x4 o;
  o[0] = (bf16_t)((v.x - mu) * rstd * gv.x + bv.x);
  o[1] = (bf16_t)((v.y - mu) * rstd * gv.y + bv.y);
  o[2] = (bf16_t)((v.z - mu) * rstd * gv.z + bv.z);
  o[3] = (bf16_t)((v.w - mu) * rstd * gv.w + bv.w);
  *(bf16x4*)(out + (size_t)row * CC + tid * 4) = o;
}

// C = A[M,K] @ Bt[N,K]^T ; A,Bt bf16 row-major. 128x128 tile, BK=32, 4 waves.
// EPI: 0 = bf16 store; 1 = bf16 store of relu(acc+bias); 2 = f32 store of acc+bias+res
// EPI: 3 = bf16 store, but cols >= 2048 go transposed to vt[bh][d][T] (QKV fused V-transpose)
template <int EPI>
__global__ __launch_bounds__(256) void gemm_bt(const bf16_t* __restrict__ A,
                                               const bf16_t* __restrict__ Bt,
                                               void* __restrict__ Cout,
                                               const float* __restrict__ bias,
                                               const float* __restrict__ res,
                                               bf16_t* __restrict__ vt,
                                               int M, int N, int K) {
  __shared__ alignas(16) bf16_t As[128 * 32];
  __shared__ alignas(16) bf16_t Bs[128 * 32];
  const int tid = threadIdx.x;
  const int wave = tid >> 6, lane = tid & 63;
  const int lr = lane & 15, lg = lane >> 4;
  const int wm = wave >> 1, wn = wave & 1;
  const int tm0 = blockIdx.y * 128, tn0 = blockIdx.x * 128;

  const int r0 = wave * 32 + (lane >> 2);
  const int kc = (lane & 3) * 8;
  const bf16_t* Ag0 = A + (size_t)(tm0 + r0) * K + kc;
  const bf16_t* Ag1 = Ag0 + (size_t)16 * K;
  const bf16_t* Bg0 = Bt + (size_t)(tn0 + r0) * K + kc;
  const bf16_t* Bg1 = Bg0 + (size_t)16 * K;
  bf16_t* Al = As + (size_t)(wave * 2) * 512;
  bf16_t* Bl = Bs + (size_t)(wave * 2) * 512;

  f32x4 acc[4][4] = {};
  for (int k0 = 0; k0 < K; k0 += 32) {
    gld_lds16(Ag0 + k0, Al);
    gld_lds16(Ag1 + k0, Al + 512);
    gld_lds16(Bg0 + k0, Bl);
    gld_lds16(Bg1 + k0, Bl + 512);
    __syncthreads();
    bf16x8 af[4], bfr[4];
#pragma unroll
    for (int m = 0; m < 4; ++m)
      af[m] = *(const bf16x8*)&As[(wm * 64 + m * 16 + lr) * 32 + lg * 8];
#pragma unroll
    for (int n = 0; n < 4; ++n)
      bfr[n] = *(const bf16x8*)&Bs[(wn * 64 + n * 16 + lr) * 32 + lg * 8];
#pragma unroll
    for (int m = 0; m < 4; ++m)
#pragma unroll
      for (int n = 0; n < 4; ++n)
        acc[m][n] = __builtin_amdgcn_mfma_f32_16x16x32_bf16(af[m], bfr[n], acc[m][n], 0, 0, 0);
    __syncthreads();
  }
#pragma unroll
  for (int m = 0; m < 4; ++m) {
#pragma unroll
    for (int i = 0; i < 4; ++i) {
      const int row = tm0 + wm * 64 + m * 16 + lg * 4 + i;
#pragma unroll
      for (int n = 0; n < 4; ++n) {
        const int col = tn0 + wn * 64 + n * 16 + lr;
        float v = acc[m][n][i];
        if (EPI == 1) v = fmaxf(v + bias[col], 0.f);
        if (EPI == 2) v = v + bias[col] + res[(size_t)row * N + col];
        if (EPI == 2) {
          ((float*)Cout)[(size_t)row * N + col] = v;
        } else if (EPI == 3) {
          if (col >= 2048) {
            const int hd = col - 2048;  // h*64 + d
            const size_t vidx =
                ((size_t)((row >> 11) * 16 + (hd >> 6)) * 64 + (hd & 63)) * TT + (row & (TT - 1));
            vt[vidx] = (bf16_t)v;
          } else {
            ((bf16_t*)Cout)[(size_t)row * N + col] = (bf16_t)v;
          }
        } else {
          ((bf16_t*)Cout)[(size_t)row * N + col] = (bf16_t)v;
        }
      }
    }
  }
}

// Flash attention, causal, D=64, T=2048. 4 waves per block, q-tile 64 rows (16/wave).
// K and V^T cooperatively staged into padded LDS ([64][72], 144B rows -> conflict-free
// b128 on both write and fragment-read). T14 split: next-tile global loads issued at
// iteration top, ds_write after barrier. KVBLK=64, 2 barriers/iter. scale = 1/32.
__global__ __launch_bounds__(256, 4) void attn_fwd(const bf16_t* __restrict__ qkv,
                                                   const bf16_t* __restrict__ Vt,
                                                   bf16_t* __restrict__ O) {
  const int bh = blockIdx.y;
  const int bb = bh >> 4, hh = bh & 15;
  const int bx = blockIdx.x;
  const int qt = (bx & 1) ? (31 - (bx >> 1)) : (bx >> 1);  // pair heavy+light tiles
  const int qbase = qt * 64;
  const int tid = threadIdx.x;
  const int wave = tid >> 6, lane = tid & 63;
  const int lr = lane & 15, lg = lane >> 4;
  const bf16_t* Qp = qkv + (size_t)bb * TT * 3072 + hh * 64;
  const bf16_t* Kp = Qp + 1024;
  const bf16_t* Vh = Vt + (size_t)bh * 64 * TT;

  constexpr int LDP = 72;  // padded row stride (elems); 144B = 36 words, conflict-free
  __shared__ alignas(16) bf16_t Klds[64 * LDP];
  __shared__ alignas(16) bf16_t Vlds[64 * LDP];
  __shared__ alignas(16) bf16_t PlS[4][16][64];  // per-wave P tile, XOR-swizzled cols
  bf16_t* Pw = &PlS[wave][0][0];

  // staging geometry: wave w, instr i in {0,1}: row = w*16 + i*8 + (lane>>3),
  // col chunk = (lane&7)*8 elems (16B). 8 rows x 128B per instr per wave.
  const int srow0 = wave * 16 + (lane >> 3);
  const int scol = (lane & 7) * 8;

  const int qrow = qbase + wave * 16;
  const bf16x8 qf0 = *(const bf16x8*)(Qp + (size_t)(qrow + lr) * 3072 + lg * 8);
  const bf16x8 qf1 = *(const bf16x8*)(Qp + (size_t)(qrow + lr) * 3072 + 32 + lg * 8);

  f32x4 oacc[4] = {};
  float m_r[4], l_r[4];
#pragma unroll
  for (int i = 0; i < 4; ++i) { m_r[i] = -1e38f; l_r[i] = 0.f; }

  const float scale = 0.03125f;

  // ---- prologue: stage tile s0=0 ----
  bf16x8 kpre[2], vpre[2];
#pragma unroll
  for (int i = 0; i < 2; ++i) {
    kpre[i] = *(const bf16x8*)(Kp + (size_t)(srow0 + i * 8) * 3072 + scol);
    vpre[i] = *(const bf16x8*)(Vh + (size_t)(srow0 + i * 8) * TT + scol);
  }
#pragma unroll
  for (int i = 0; i < 2; ++i) {
    *(bf16x8*)&Klds[(srow0 + i * 8) * LDP + scol] = kpre[i];
    *(bf16x8*)&Vlds[(srow0 + i * 8) * LDP + scol] = vpre[i];
  }
  __syncthreads();

  for (int s0 = 0; s0 <= qbase; s0 += 64) {
    // ---- issue next-tile global loads (in flight across this iteration) ----
    const int snext = (s0 + 64 <= qbase) ? s0 + 64 : s0;
#pragma unroll
    for (int i = 0; i < 2; ++i) {
      kpre[i] = *(const bf16x8*)(Kp + (size_t)(snext + srow0 + i * 8) * 3072 + scol);
      vpre[i] = *(const bf16x8*)(Vh + (size_t)(srow0 + i * 8) * TT + snext + scol);
    }

    // ---- QK^T: 4 chunks of 16 s, k=64, K from LDS ----
    float P[4][4];
    __builtin_amdgcn_s_setprio(1);
#pragma unroll
    for (int ct = 0; ct < 4; ++ct) {
      const bf16x8 kf0 = *(const bf16x8*)&Klds[(ct * 16 + lr) * LDP + lg * 8];
      const bf16x8 kf1 = *(const bf16x8*)&Klds[(ct * 16 + lr) * LDP + 32 + lg * 8];
      f32x4 z = {};
      z = __builtin_amdgcn_mfma_f32_16x16x32_bf16(qf0, kf0, z, 0, 0, 0);
      z = __builtin_amdgcn_mfma_f32_16x16x32_bf16(qf1, kf1, z, 0, 0, 0);
      const int sg = s0 + ct * 16 + lr;
#pragma unroll
      for (int i = 0; i < 4; ++i) {
        float sv = z[i] * scale;
        if (sg > qrow + lg * 4 + i) sv = -1e30f;  // causal mask
        P[ct][i] = sv;
      }
    }
    __builtin_amdgcn_s_setprio(0);

    // ---- online softmax over 64 s ----
    float rm[4], alpha[4], lad[4];
#pragma unroll
    for (int i = 0; i < 4; ++i)
      rm[i] = fmaxf(fmaxf(P[0][i], P[1][i]), fmaxf(P[2][i], P[3][i]));
#pragma unroll
    for (int off = 1; off < 16; off <<= 1)
#pragma unroll
      for (int i = 0; i < 4; ++i) rm[i] = fmaxf(rm[i], __shfl_xor(rm[i], off));
#pragma unroll
    for (int i = 0; i < 4; ++i) {
      const float mn = fmaxf(m_r[i], rm[i]);
      alpha[i] = __expf(m_r[i] - mn);
      m_r[i] = mn;
      float acc_l = 0.f;
#pragma unroll
      for (int ct = 0; ct < 4; ++ct) {
        const float p = __expf(P[ct][i] - mn);
        P[ct][i] = p;
        acc_l += p;
      }
      lad[i] = acc_l;
    }
#pragma unroll
    for (int off = 1; off < 16; off <<= 1)
#pragma unroll
      for (int i = 0; i < 4; ++i) lad[i] += __shfl_xor(lad[i], off);
#pragma unroll
    for (int i = 0; i < 4; ++i) l_r[i] = l_r[i] * alpha[i] + lad[i];

    // ---- P -> LDS (XOR-swizzled; R3-verified conflict-free) ----
#pragma unroll
    for (int ct = 0; ct < 4; ++ct)
#pragma unroll
      for (int i = 0; i < 4; ++i) {
        const int q = lg * 4 + i;
        const int col = (ct * 16 + lr) ^ ((q & 7) << 3);
        Pw[q * 64 + col] = (bf16_t)P[ct][i];
      }
    asm volatile("s_waitcnt lgkmcnt(0)" ::: "memory");
    __builtin_amdgcn_sched_barrier(0);

    // ---- rescale O, then PV (V from LDS) ----
#pragma unroll
    for (int db = 0; db < 4; ++db)
#pragma unroll
      for (int i = 0; i < 4; ++i) oacc[db][i] *= alpha[i];

    __builtin_amdgcn_s_setprio(1);
#pragma unroll
    for (int kc = 0; kc < 2; ++kc) {
      const bf16x8 pf = *(const bf16x8*)&Pw[lr * 64 + ((kc * 32 + lg * 8) ^ ((lr & 7) << 3))];
#pragma unroll
      for (int db = 0; db < 4; ++db) {
        const bf16x8 vf = *(const bf16x8*)&Vlds[(db * 16 + lr) * LDP + kc * 32 + lg * 8];
        oacc[db] = __builtin_amdgcn_mfma_f32_16x16x32_bf16(pf, vf, oacc[db], 0, 0, 0);
      }
    }
    __builtin_amdgcn_s_setprio(0);

    // ---- publish next tile ----
    __syncthreads();  // all LDS reads of current tile done
#pragma unroll
    for (int i = 0; i < 2; ++i) {
      *(bf16x8*)&Klds[(srow0 + i * 8) * LDP + scol] = kpre[i];
      *(bf16x8*)&Vlds[(srow0 + i * 8) * LDP + scol] = vpre[i];
    }
    __syncthreads();  // writes visible
  }

  bf16_t* Op = O + ((size_t)bb * TT + qrow) * CC + hh * 64;
#pragma unroll
  for (int db = 0; db < 4; ++db)
#pragma unroll
    for (int i = 0; i < 4; ++i)
      Op[(size_t)(lg * 4 + i) * CC + db * 16 + lr] = (bf16_t)(oacc[db][i] / l_r[i]);
}

extern "C" void kernel_launch(void* const* d_in, const int* in_sizes, int n_in,
                              void* d_out, int out_size, void* d_ws, size_t ws_size,
                              hipStream_t stream) {
  const float* x      = (const float*)d_in[0];
  const float* wq     = (const float*)d_in[1];
  const float* wk     = (const float*)d_in[2];
  const float* wv     = (const float*)d_in[3];
  const float* w_proj = (const float*)d_in[4];
  const float* b_proj = (const float*)d_in[5];
  const float* w1     = (const float*)d_in[6];
  const float* b1     = (const float*)d_in[7];
  const float* w2     = (const float*)d_in[8];
  const float* b2     = (const float*)d_in[9];
  const float* ln1_g  = (const float*)d_in[10];
  const float* ln1_b  = (const float*)d_in[11];
  const float* ln2_g  = (const float*)d_in[12];
  const float* ln2_b  = (const float*)d_in[13];

  char* ws = (char*)d_ws;
  const size_t MB = 1024 * 1024;
  bf16_t* h1    = (bf16_t*)(ws + 0);         // 8 MB  [4096][1024]
  bf16_t* Bqkv  = (bf16_t*)(ws + 8 * MB);    // 6 MB  [3072][1024]
  bf16_t* Bproj = (bf16_t*)(ws + 14 * MB);   // 2 MB  [1024][1024]
  bf16_t* B1w   = (bf16_t*)(ws + 16 * MB);   // 8 MB  [4096][1024]
  bf16_t* B2w   = (bf16_t*)(ws + 24 * MB);   // 8 MB  [1024][4096]
  bf16_t* qkv   = (bf16_t*)(ws + 32 * MB);   // 24 MB [4096][3072] (V region unused)
  bf16_t* Obuf  = (bf16_t*)(ws + 56 * MB);   // 8 MB  [4096][1024]
  float*  res1  = (float*)(ws + 64 * MB);    // 16 MB [4096][1024], written AFTER attn
  bf16_t* Vt    = (bf16_t*)(ws + 64 * MB);   // 16 MB [32][64][2048], dead once attn done
  bf16_t* h2    = (bf16_t*)(ws + 80 * MB);   // 8 MB  [4096][1024]
  bf16_t* a1    = (bf16_t*)(ws + 32 * MB);   // 32 MB [4096][4096], reuses qkv+Obuf
  float*  outp  = (float*)d_out;

  dim3 blk(256);
  // weight prep: Bt[n][k] layouts
  transpose_cvt<<<dim3(32, 2, 16), blk, 0, stream>>>(wq, Bqkv, 1024, 64);
  transpose_cvt<<<dim3(32, 2, 16), blk, 0, stream>>>(wk, Bqkv + 1024 * 1024, 1024, 64);
  transpose_cvt<<<dim3(32, 2, 16), blk, 0, stream>>>(wv, Bqkv + 2 * 1024 * 1024, 1024, 64);
  transpose_cvt<<<dim3(32, 32, 1), blk, 0, stream>>>(w_proj, Bproj, 1024, 1024);
  transpose_cvt<<<dim3(32, 128, 1), blk, 0, stream>>>(w1, B1w, 1024, 4096);
  transpose_cvt<<<dim3(128, 32, 1), blk, 0, stream>>>(w2, B2w, 4096, 1024);

  ln_f32_bf16<<<dim3(4096), blk, 0, stream>>>(x, ln1_g, ln1_b, h1);
  gemm_bt<3><<<dim3(24, 32), blk, 0, stream>>>(h1, Bqkv, qkv, nullptr, nullptr, Vt, 4096, 3072, 1024);
  attn_fwd<<<dim3(32, 32), blk, 0, stream>>>(qkv, Vt, Obuf);
  gemm_bt<2><<<dim3(8, 32), blk, 0, stream>>>(Obuf, Bproj, res1, b_proj, x, nullptr, 4096, 1024, 1024);
  ln_f32_bf16<<<dim3(4096), blk, 0, stream>>>(res1, ln2_g, ln2_b, h2);
  gemm_bt<1><<<dim3(32, 32), blk, 0, stream>>>(h2, B1w, a1, b1, nullptr, nullptr, 4096, 4096, 1024);
  gemm_bt<2><<<dim3(8, 32), blk, 0, stream>>>(a1, B2w, outp, b2, res1, nullptr, 4096, 1024, 4096);
}

// Round 5
// 302.670 us; speedup vs baseline: 1.7688x; 1.2037x over previous
//
#include <hip/hip_runtime.h>
#include <hip/hip_bf16.h>
#include <stdint.h>

typedef __bf16 bf16_t;
typedef __bf16 bf16x8 __attribute__((ext_vector_type(8)));
typedef __bf16 bf16x4 __attribute__((ext_vector_type(4)));
typedef float f32x4 __attribute__((ext_vector_type(4)));

static constexpr int TT = 2048, CC = 1024;

__device__ __forceinline__ void gld_lds16(const void* g, void* l) {
  __builtin_amdgcn_global_load_lds((const __attribute__((address_space(1))) void*)g,
                                   (__attribute__((address_space(3))) void*)l, 16, 0, 0);
}

// out[n][k] = (bf16) in[k][n]; per-batch stride K*N both sides
__global__ __launch_bounds__(256) void transpose_cvt(const float* __restrict__ in,
                                                     bf16_t* __restrict__ out,
                                                     int K, int N) {
  __shared__ float t[32][33];
  const int k0 = blockIdx.x * 32, n0 = blockIdx.y * 32;
  const size_t boff = (size_t)blockIdx.z * K * N;
  in += boff;
  out += boff;
  const int tx = threadIdx.x & 31, ty = threadIdx.x >> 5;
#pragma unroll
  for (int j = 0; j < 4; ++j)
    t[ty + j * 8][tx] = in[(size_t)(k0 + ty + j * 8) * N + n0 + tx];
  __syncthreads();
#pragma unroll
  for (int j = 0; j < 4; ++j)
    out[(size_t)(n0 + ty + j * 8) * K + k0 + tx] = (bf16_t)t[tx][ty + j * 8];
}

// LayerNorm over C=1024, one block (256 thr) per row, bf16 out
__global__ __launch_bounds__(256) void ln_f32_bf16(const float* __restrict__ x,
                                                   const float* __restrict__ g,
                                                   const float* __restrict__ b,
                                                   bf16_t* __restrict__ out) {
  const int row = blockIdx.x;
  const int tid = threadIdx.x;
  const float4 v = ((const float4*)(x + (size_t)row * CC))[tid];
  float s = v.x + v.y + v.z + v.w;
  float q = v.x * v.x + v.y * v.y + v.z * v.z + v.w * v.w;
#pragma unroll
  for (int off = 1; off < 64; off <<= 1) {
    s += __shfl_xor(s, off);
    q += __shfl_xor(q, off);
  }
  __shared__ float red[8];
  const int wave = tid >> 6, lane = tid & 63;
  if (lane == 0) { red[wave] = s; red[4 + wave] = q; }
  __syncthreads();
  s = red[0] + red[1] + red[2] + red[3];
  q = red[4] + red[5] + red[6] + red[7];
  const float mu = s * (1.0f / CC);
  float var = q * (1.0f / CC) - mu * mu;
  var = fmaxf(var, 0.f);
  const float rstd = rsqrtf(var + 1e-5f);
  const float4 gv = ((const float4*)g)[tid];
  const float4 bv = ((const float4*)b)[tid];
  bf16x4 o;
  o[0] = (bf16_t)((v.x - mu) * rstd * gv.x + bv.x);
  o[1] = (bf16_t)((v.y - mu) * rstd * gv.y + bv.y);
  o[2] = (bf16_t)((v.z - mu) * rstd * gv.z + bv.z);
  o[3] = (bf16_t)((v.w - mu) * rstd * gv.w + bv.w);
  *(bf16x4*)(out + (size_t)row * CC + tid * 4) = o;
}

// C = A[M,K] @ Bt[N,K]^T ; A,Bt bf16 row-major. 128x128 tile, BK=32, 4 waves.
// EPI: 0 = bf16 store; 1 = bf16 store of relu(acc+bias); 2 = f32 store of acc+bias+res
// EPI: 3 = bf16 store, but cols >= 2048 go transposed to vt[bh][d][T] (QKV fused V-transpose)
template <int EPI>
__global__ __launch_bounds__(256) void gemm_bt(const bf16_t* __restrict__ A,
                                               const bf16_t* __restrict__ Bt,
                                               void* __restrict__ Cout,
                                               const float* __restrict__ bias,
                                               const float* __restrict__ res,
                                               bf16_t* __restrict__ vt,
                                               int M, int N, int K) {
  __shared__ alignas(16) bf16_t As[128 * 32];
  __shared__ alignas(16) bf16_t Bs[128 * 32];
  const int tid = threadIdx.x;
  const int wave = tid >> 6, lane = tid & 63;
  const int lr = lane & 15, lg = lane >> 4;
  const int wm = wave >> 1, wn = wave & 1;
  const int tm0 = blockIdx.y * 128, tn0 = blockIdx.x * 128;

  const int r0 = wave * 32 + (lane >> 2);
  const int kc = (lane & 3) * 8;
  const bf16_t* Ag0 = A + (size_t)(tm0 + r0) * K + kc;
  const bf16_t* Ag1 = Ag0 + (size_t)16 * K;
  const bf16_t* Bg0 = Bt + (size_t)(tn0 + r0) * K + kc;
  const bf16_t* Bg1 = Bg0 + (size_t)16 * K;
  bf16_t* Al = As + (size_t)(wave * 2) * 512;
  bf16_t* Bl = Bs + (size_t)(wave * 2) * 512;

  f32x4 acc[4][4] = {};
  for (int k0 = 0; k0 < K; k0 += 32) {
    gld_lds16(Ag0 + k0, Al);
    gld_lds16(Ag1 + k0, Al + 512);
    gld_lds16(Bg0 + k0, Bl);
    gld_lds16(Bg1 + k0, Bl + 512);
    __syncthreads();
    bf16x8 af[4], bfr[4];
#pragma unroll
    for (int m = 0; m < 4; ++m)
      af[m] = *(const bf16x8*)&As[(wm * 64 + m * 16 + lr) * 32 + lg * 8];
#pragma unroll
    for (int n = 0; n < 4; ++n)
      bfr[n] = *(const bf16x8*)&Bs[(wn * 64 + n * 16 + lr) * 32 + lg * 8];
#pragma unroll
    for (int m = 0; m < 4; ++m)
#pragma unroll
      for (int n = 0; n < 4; ++n)
        acc[m][n] = __builtin_amdgcn_mfma_f32_16x16x32_bf16(af[m], bfr[n], acc[m][n], 0, 0, 0);
    __syncthreads();
  }
#pragma unroll
  for (int m = 0; m < 4; ++m) {
#pragma unroll
    for (int i = 0; i < 4; ++i) {
      const int row = tm0 + wm * 64 + m * 16 + lg * 4 + i;
#pragma unroll
      for (int n = 0; n < 4; ++n) {
        const int col = tn0 + wn * 64 + n * 16 + lr;
        float v = acc[m][n][i];
        if (EPI == 1) v = fmaxf(v + bias[col], 0.f);
        if (EPI == 2) v = v + bias[col] + res[(size_t)row * N + col];
        if (EPI == 2) {
          ((float*)Cout)[(size_t)row * N + col] = v;
        } else if (EPI == 3) {
          if (col >= 2048) {
            const int hd = col - 2048;  // h*64 + d
            const size_t vidx =
                ((size_t)((row >> 11) * 16 + (hd >> 6)) * 64 + (hd & 63)) * TT + (row & (TT - 1));
            vt[vidx] = (bf16_t)v;
          } else {
            ((bf16_t*)Cout)[(size_t)row * N + col] = (bf16_t)v;
          }
        } else {
          ((bf16_t*)Cout)[(size_t)row * N + col] = (bf16_t)v;
        }
      }
    }
  }
}

// Flash attention, causal, D=64, T=2048. 4 waves/block, q-tile 64 rows (16/wave).
// KVBLK=128; K[s][d] and V^T[d][s] cooperatively staged (async split); per-wave P
// tile [16][136] with col^=(q>>3)<<4 (write banks free). LPT grid (heavy first),
// chunk-skip on diagonal, defer-max THR=8, l-reduce deferred to epilogue.
// Q pre-scaled by 2^-5 (exact in bf16).
__global__ __launch_bounds__(256, 3) void attn_fwd(const bf16_t* __restrict__ qkv,
                                                   const bf16_t* __restrict__ Vt,
                                                   bf16_t* __restrict__ O) {
  const int bh = blockIdx.x;
  const int bb = bh >> 4, hh = bh & 15;
  const int qt = 31 - (int)blockIdx.y;  // LPT: heaviest first
  const int qbase = qt * 64;
  const int tid = threadIdx.x;
  const int wave = tid >> 6, lane = tid & 63;
  const int lr = lane & 15, lg = lane >> 4;
  const bf16_t* Qp = qkv + (size_t)bb * TT * 3072 + hh * 64;
  const bf16_t* Kp = Qp + 1024;
  const bf16_t* Vh = Vt + (size_t)bh * 64 * TT;

  constexpr int KLP = 72;   // K tile [128 s][72]
  constexpr int VLP = 136;  // V^T tile [64 d][136]
  constexpr int PLP = 136;  // P tile [16 q][136] per wave
  __shared__ alignas(16) bf16_t Klds[128 * KLP];
  __shared__ alignas(16) bf16_t Vlds[64 * VLP];
  __shared__ alignas(16) bf16_t PlS[4][16 * PLP];
  bf16_t* Pw = PlS[wave];

  // staging geometry (per wave: K 4x8 rows of 128B, V 4x4 rows of 256B)
  const int ksr = wave * 32 + (lane >> 3);
  const int ksc = (lane & 7) * 8;
  const int vsr = wave * 16 + (lane >> 4);
  const int vsc = (lane & 15) * 8;

  const int qrow = qbase + wave * 16;
  bf16x8 qf0, qf1;
  {
    const bf16x8 a = *(const bf16x8*)(Qp + (size_t)(qrow + lr) * 3072 + lg * 8);
    const bf16x8 b = *(const bf16x8*)(Qp + (size_t)(qrow + lr) * 3072 + 32 + lg * 8);
#pragma unroll
    for (int j = 0; j < 8; ++j) {
      qf0[j] = (bf16_t)((float)a[j] * 0.03125f);
      qf1[j] = (bf16_t)((float)b[j] * 0.03125f);
    }
  }

  f32x4 oacc[4] = {};
  float m_r[4], l_r[4];
#pragma unroll
  for (int i = 0; i < 4; ++i) { m_r[i] = -1e38f; l_r[i] = 0.f; }

  bf16x8 kpre[4], vpre[4];
  // prologue: stage tile 0
#pragma unroll
  for (int i = 0; i < 4; ++i) {
    kpre[i] = *(const bf16x8*)(Kp + (size_t)(ksr + i * 8) * 3072 + ksc);
    vpre[i] = *(const bf16x8*)(Vh + (size_t)(vsr + i * 4) * TT + vsc);
  }
#pragma unroll
  for (int i = 0; i < 4; ++i) {
    *(bf16x8*)&Klds[(ksr + i * 8) * KLP + ksc] = kpre[i];
    *(bf16x8*)&Vlds[(vsr + i * 4) * VLP + vsc] = vpre[i];
  }
  __syncthreads();

  const int nt = (qt >> 1) + 1;
  for (int t = 0; t < nt; ++t) {
    const int s0 = t * 128;
    // issue next-tile loads (stay in flight across this iteration)
    const int sn = (t + 1 < nt) ? s0 + 128 : s0;
#pragma unroll
    for (int i = 0; i < 4; ++i) {
      kpre[i] = *(const bf16x8*)(Kp + (size_t)(sn + ksr + i * 8) * 3072 + ksc);
      vpre[i] = *(const bf16x8*)(Vh + (size_t)(vsr + i * 4) * TT + sn + vsc);
    }

    const int u = (qrow - s0) >> 4;       // # fully-unmasked 16-chunks (wave-uniform)
    const int cmc = min(u | 1, 7);        // last computed chunk (odd, <=7)

    // ---- QK^T over up to 128 s ----
    float P[8][4];
    __builtin_amdgcn_s_setprio(1);
#pragma unroll
    for (int ct = 0; ct < 8; ++ct) {
      if (ct <= cmc) {
        const bf16x8 kf0 = *(const bf16x8*)&Klds[(ct * 16 + lr) * KLP + lg * 8];
        const bf16x8 kf1 = *(const bf16x8*)&Klds[(ct * 16 + lr) * KLP + 32 + lg * 8];
        f32x4 z = {};
        z = __builtin_amdgcn_mfma_f32_16x16x32_bf16(qf0, kf0, z, 0, 0, 0);
        z = __builtin_amdgcn_mfma_f32_16x16x32_bf16(qf1, kf1, z, 0, 0, 0);
        if (ct >= u) {
          const int sg = s0 + ct * 16 + lr;
#pragma unroll
          for (int i = 0; i < 4; ++i)
            P[ct][i] = (sg > qrow + lg * 4 + i) ? -1e30f : z[i];
        } else {
#pragma unroll
          for (int i = 0; i < 4; ++i) P[ct][i] = z[i];
        }
      } else {
#pragma unroll
        for (int i = 0; i < 4; ++i) P[ct][i] = -1e30f;
      }
    }
    __builtin_amdgcn_s_setprio(0);

    // ---- local max + defer-max check (no shuffle on deferred path) ----
    float lmax[4];
#pragma unroll
    for (int i = 0; i < 4; ++i) {
      float m0 = fmaxf(fmaxf(P[0][i], P[1][i]), fmaxf(P[2][i], P[3][i]));
      float m1 = fmaxf(fmaxf(P[4][i], P[5][i]), fmaxf(P[6][i], P[7][i]));
      lmax[i] = fmaxf(m0, m1);
    }
    const bool ok = (lmax[0] <= m_r[0] + 8.f) && (lmax[1] <= m_r[1] + 8.f) &&
                    (lmax[2] <= m_r[2] + 8.f) && (lmax[3] <= m_r[3] + 8.f);
    if (!__all(ok)) {
      float rm[4] = {lmax[0], lmax[1], lmax[2], lmax[3]};
#pragma unroll
      for (int off = 1; off < 16; off <<= 1)
#pragma unroll
        for (int i = 0; i < 4; ++i) rm[i] = fmaxf(rm[i], __shfl_xor(rm[i], off));
#pragma unroll
      for (int i = 0; i < 4; ++i) {
        const float mn = fmaxf(m_r[i], rm[i]);
        const float alpha = __expf(m_r[i] - mn);
        m_r[i] = mn;
        l_r[i] *= alpha;
#pragma unroll
        for (int db = 0; db < 4; ++db) oacc[db][i] *= alpha;
      }
    }

    // ---- exp + per-lane partial l (cross-lane l-reduce deferred to epilogue) ----
#pragma unroll
    for (int i = 0; i < 4; ++i) {
      float ls = 0.f;
#pragma unroll
      for (int ct = 0; ct < 8; ++ct) {
        const float p = __expf(P[ct][i] - m_r[i]);
        P[ct][i] = p;
        ls += p;
      }
      l_r[i] += ls;
    }

    // ---- P -> LDS (padded + q-swizzled cols; conflict-free writes) ----
#pragma unroll
    for (int ct = 0; ct < 8; ++ct) {
      if (ct <= cmc) {
#pragma unroll
        for (int i = 0; i < 4; ++i) {
          const int q = lg * 4 + i;
          const int col = (ct * 16 + lr) ^ ((lg >> 1) << 4);
          Pw[q * PLP + col] = (bf16_t)P[ct][i];
        }
      }
    }
    asm volatile("s_waitcnt lgkmcnt(0)" ::: "memory");
    __builtin_amdgcn_sched_barrier(0);

    // ---- PV (kc clipped to computed chunks) ----
    const int kcm = cmc >> 1;
    __builtin_amdgcn_s_setprio(1);
#pragma unroll
    for (int kc = 0; kc < 4; ++kc) {
      if (kc <= kcm) {
        const bf16x8 pf =
            *(const bf16x8*)&Pw[lr * PLP + ((kc * 32 + lg * 8) ^ ((lr >> 3) << 4))];
#pragma unroll
        for (int db = 0; db < 4; ++db) {
          const bf16x8 vf = *(const bf16x8*)&Vlds[(db * 16 + lr) * VLP + kc * 32 + lg * 8];
          oacc[db] = __builtin_amdgcn_mfma_f32_16x16x32_bf16(pf, vf, oacc[db], 0, 0, 0);
        }
      }
    }
    __builtin_amdgcn_s_setprio(0);

    // ---- publish next tile ----
    if (t + 1 < nt) {
      __syncthreads();
#pragma unroll
      for (int i = 0; i < 4; ++i) {
        *(bf16x8*)&Klds[(ksr + i * 8) * KLP + ksc] = kpre[i];
        *(bf16x8*)&Vlds[(vsr + i * 4) * VLP + vsc] = vpre[i];
      }
      __syncthreads();
    }
  }

  // epilogue: reduce l across the 16 s-owner lanes, then store O = oacc/l
#pragma unroll
  for (int off = 1; off < 16; off <<= 1)
#pragma unroll
    for (int i = 0; i < 4; ++i) l_r[i] += __shfl_xor(l_r[i], off);

  bf16_t* Op = O + ((size_t)bb * TT + qrow) * CC + hh * 64;
#pragma unroll
  for (int i = 0; i < 4; ++i) {
    const float rl = 1.0f / l_r[i];
#pragma unroll
    for (int db = 0; db < 4; ++db)
      Op[(size_t)(lg * 4 + i) * CC + db * 16 + lr] = (bf16_t)(oacc[db][i] * rl);
  }
}

extern "C" void kernel_launch(void* const* d_in, const int* in_sizes, int n_in,
                              void* d_out, int out_size, void* d_ws, size_t ws_size,
                              hipStream_t stream) {
  const float* x      = (const float*)d_in[0];
  const float* wq     = (const float*)d_in[1];
  const float* wk     = (const float*)d_in[2];
  const float* wv     = (const float*)d_in[3];
  const float* w_proj = (const float*)d_in[4];
  const float* b_proj = (const float*)d_in[5];
  const float* w1     = (const float*)d_in[6];
  const float* b1     = (const float*)d_in[7];
  const float* w2     = (const float*)d_in[8];
  const float* b2     = (const float*)d_in[9];
  const float* ln1_g  = (const float*)d_in[10];
  const float* ln1_b  = (const float*)d_in[11];
  const float* ln2_g  = (const float*)d_in[12];
  const float* ln2_b  = (const float*)d_in[13];

  char* ws = (char*)d_ws;
  const size_t MB = 1024 * 1024;
  bf16_t* h1    = (bf16_t*)(ws + 0);         // 8 MB  [4096][1024]
  bf16_t* Bqkv  = (bf16_t*)(ws + 8 * MB);    // 6 MB  [3072][1024]
  bf16_t* Bproj = (bf16_t*)(ws + 14 * MB);   // 2 MB  [1024][1024]
  bf16_t* B1w   = (bf16_t*)(ws + 16 * MB);   // 8 MB  [4096][1024]
  bf16_t* B2w   = (bf16_t*)(ws + 24 * MB);   // 8 MB  [1024][4096]
  bf16_t* qkv   = (bf16_t*)(ws + 32 * MB);   // 24 MB [4096][3072] (V region unused)
  bf16_t* Obuf  = (bf16_t*)(ws + 56 * MB);   // 8 MB  [4096][1024]
  float*  res1  = (float*)(ws + 64 * MB);    // 16 MB [4096][1024], written AFTER attn
  bf16_t* Vt    = (bf16_t*)(ws + 64 * MB);   // 16 MB [32][64][2048], dead once attn done
  bf16_t* h2    = (bf16_t*)(ws + 80 * MB);   // 8 MB  [4096][1024]
  bf16_t* a1    = (bf16_t*)(ws + 32 * MB);   // 32 MB [4096][4096], reuses qkv+Obuf
  float*  outp  = (float*)d_out;

  dim3 blk(256);
  // weight prep: Bt[n][k] layouts
  transpose_cvt<<<dim3(32, 2, 16), blk, 0, stream>>>(wq, Bqkv, 1024, 64);
  transpose_cvt<<<dim3(32, 2, 16), blk, 0, stream>>>(wk, Bqkv + 1024 * 1024, 1024, 64);
  transpose_cvt<<<dim3(32, 2, 16), blk, 0, stream>>>(wv, Bqkv + 2 * 1024 * 1024, 1024, 64);
  transpose_cvt<<<dim3(32, 32, 1), blk, 0, stream>>>(w_proj, Bproj, 1024, 1024);
  transpose_cvt<<<dim3(32, 128, 1), blk, 0, stream>>>(w1, B1w, 1024, 4096);
  transpose_cvt<<<dim3(128, 32, 1), blk, 0, stream>>>(w2, B2w, 4096, 1024);

  ln_f32_bf16<<<dim3(4096), blk, 0, stream>>>(x, ln1_g, ln1_b, h1);
  gemm_bt<3><<<dim3(24, 32), blk, 0, stream>>>(h1, Bqkv, qkv, nullptr, nullptr, Vt, 4096, 3072, 1024);
  attn_fwd<<<dim3(32, 32), blk, 0, stream>>>(qkv, Vt, Obuf);
  gemm_bt<2><<<dim3(8, 32), blk, 0, stream>>>(Obuf, Bproj, res1, b_proj, x, nullptr, 4096, 1024, 1024);
  ln_f32_bf16<<<dim3(4096), blk, 0, stream>>>(res1, ln2_g, ln2_b, h2);
  gemm_bt<1><<<dim3(32, 32), blk, 0, stream>>>(h2, B1w, a1, b1, nullptr, nullptr, 4096, 4096, 1024);
  gemm_bt<2><<<dim3(8, 32), blk, 0, stream>>>(a1, B2w, outp, b2, res1, nullptr, 4096, 1024, 4096);
}

// Round 7
// 269.587 us; speedup vs baseline: 1.9859x; 1.1227x over previous
//
#include <hip/hip_runtime.h>
#include <hip/hip_bf16.h>
#include <stdint.h>

typedef __bf16 bf16_t;
typedef __bf16 bf16x8 __attribute__((ext_vector_type(8)));
typedef __bf16 bf16x4 __attribute__((ext_vector_type(4)));
typedef float f32x4 __attribute__((ext_vector_type(4)));

static constexpr int TT = 2048, CC = 1024;

__device__ __forceinline__ void gld_lds16(const void* g, void* l) {
  __builtin_amdgcn_global_load_lds((const __attribute__((address_space(1))) void*)g,
                                   (__attribute__((address_space(3))) void*)l, 16, 0, 0);
}

// out[n][k] = (bf16) in[k][n]; per-batch stride K*N both sides
__global__ __launch_bounds__(256) void transpose_cvt(const float* __restrict__ in,
                                                     bf16_t* __restrict__ out,
                                                     int K, int N) {
  __shared__ float t[32][33];
  const int k0 = blockIdx.x * 32, n0 = blockIdx.y * 32;
  const size_t boff = (size_t)blockIdx.z * K * N;
  in += boff;
  out += boff;
  const int tx = threadIdx.x & 31, ty = threadIdx.x >> 5;
#pragma unroll
  for (int j = 0; j < 4; ++j)
    t[ty + j * 8][tx] = in[(size_t)(k0 + ty + j * 8) * N + n0 + tx];
  __syncthreads();
#pragma unroll
  for (int j = 0; j < 4; ++j)
    out[(size_t)(n0 + ty + j * 8) * K + k0 + tx] = (bf16_t)t[tx][ty + j * 8];
}

// LayerNorm over C=1024, one block (256 thr) per row, bf16 out
__global__ __launch_bounds__(256) void ln_f32_bf16(const float* __restrict__ x,
                                                   const float* __restrict__ g,
                                                   const float* __restrict__ b,
                                                   bf16_t* __restrict__ out) {
  const int row = blockIdx.x;
  const int tid = threadIdx.x;
  const float4 v = ((const float4*)(x + (size_t)row * CC))[tid];
  float s = v.x + v.y + v.z + v.w;
  float q = v.x * v.x + v.y * v.y + v.z * v.z + v.w * v.w;
#pragma unroll
  for (int off = 1; off < 64; off <<= 1) {
    s += __shfl_xor(s, off);
    q += __shfl_xor(q, off);
  }
  __shared__ float red[8];
  const int wave = tid >> 6, lane = tid & 63;
  if (lane == 0) { red[wave] = s; red[4 + wave] = q; }
  __syncthreads();
  s = red[0] + red[1] + red[2] + red[3];
  q = red[4] + red[5] + red[6] + red[7];
  const float mu = s * (1.0f / CC);
  float var = q * (1.0f / CC) - mu * mu;
  var = fmaxf(var, 0.f);
  const float rstd = rsqrtf(var + 1e-5f);
  const float4 gv = ((const float4*)g)[tid];
  const float4 bv = ((const float4*)b)[tid];
  bf16x4 o;
  o[0] = (bf16_t)((v.x - mu) * rstd * gv.x + bv.x);
  o[1] = (bf16_t)((v.y - mu) * rstd * gv.y + bv.y);
  o[2] = (bf16_t)((v.z - mu) * rstd * gv.z + bv.z);
  o[3] = (bf16_t)((v.w - mu) * rstd * gv.w + bv.w);
  *(bf16x4*)(out + (size_t)row * CC + tid * 4) = o;
}

// C = A[M,K] @ Bt[N,K]^T ; A,Bt bf16 row-major. Tile 128 x BN, BK=64, 4 waves (2x2).
// LDS rows are 64 elems (128B) with chunk XOR-swizzle c^=(row&7): global_load_lds
// writes linearly, the global SOURCE chunk is inverse-swizzled, fragment reads apply
// the same XOR -> conflict-free b128 reads at the 8-cycle floor (rule #21 pattern).
// EPI: 0 = bf16 store; 1 = bf16 relu(acc+bias); 2 = f32 acc+bias+res
// EPI: 3 = bf16 store, cols >= 2048 transposed to vt[bh][d][T] (QKV fused V-transpose)
template <int EPI, int BN>
__global__ __launch_bounds__(256) void gemm_bt(const bf16_t* __restrict__ A,
                                               const bf16_t* __restrict__ Bt,
                                               void* __restrict__ Cout,
                                               const float* __restrict__ bias,
                                               const float* __restrict__ res,
                                               bf16_t* __restrict__ vt,
                                               int M, int N, int K) {
  constexpr int WN = BN / 2;   // wave n-extent
  constexpr int NF = BN / 32;  // n-frags per wave
  constexpr int NB = BN / 32;  // B staging instrs per wave
  __shared__ alignas(16) bf16_t As[128 * 64];
  __shared__ alignas(16) bf16_t Bs[BN * 64];
  const int tid = threadIdx.x;
  const int wave = tid >> 6, lane = tid & 63;
  const int lr = lane & 15, lg = lane >> 4;
  const int wm = wave >> 1, wn = wave & 1;
  const int tm0 = blockIdx.y * 128, tn0 = blockIdx.x * BN;

  // staging: lane covers 16B chunk (sc) of row sr within a 32-row group;
  // global source chunk is sc^sr so that LDS[r][c] holds global chunk c^(r&7)
  const int sr = lane >> 3;          // 0..7
  const int scs = (lane & 7) ^ sr;   // swizzled source chunk
  const bf16_t* Ag[4];
#pragma unroll
  for (int i = 0; i < 4; ++i)
    Ag[i] = A + (size_t)(tm0 + i * 32 + wave * 8 + sr) * K + scs * 8;
  const bf16_t* Bg[NB];
#pragma unroll
  for (int i = 0; i < NB; ++i)
    Bg[i] = Bt + (size_t)(tn0 + i * 32 + wave * 8 + sr) * K + scs * 8;

  f32x4 acc[4][NF] = {};
  for (int k0 = 0; k0 < K; k0 += 64) {
#pragma unroll
    for (int i = 0; i < 4; ++i)
      gld_lds16(Ag[i] + k0, As + (i * 32 + wave * 8) * 64);
#pragma unroll
    for (int i = 0; i < NB; ++i)
      gld_lds16(Bg[i] + k0, Bs + (i * 32 + wave * 8) * 64);
    __syncthreads();
    bf16x8 af[2][4], bfr[2][NF];
#pragma unroll
    for (int kk = 0; kk < 2; ++kk) {
      const int ch = ((kk * 4 + lg) ^ (lr & 7)) * 8;
#pragma unroll
      for (int m = 0; m < 4; ++m)
        af[kk][m] = *(const bf16x8*)&As[(wm * 64 + m * 16 + lr) * 64 + ch];
#pragma unroll
      for (int n = 0; n < NF; ++n)
        bfr[kk][n] = *(const bf16x8*)&Bs[(wn * WN + n * 16 + lr) * 64 + ch];
    }
#pragma unroll
    for (int kk = 0; kk < 2; ++kk)
#pragma unroll
      for (int m = 0; m < 4; ++m)
#pragma unroll
        for (int n = 0; n < NF; ++n)
          acc[m][n] =
              __builtin_amdgcn_mfma_f32_16x16x32_bf16(af[kk][m], bfr[kk][n], acc[m][n], 0, 0, 0);
    __syncthreads();
  }
#pragma unroll
  for (int m = 0; m < 4; ++m) {
#pragma unroll
    for (int i = 0; i < 4; ++i) {
      const int row = tm0 + wm * 64 + m * 16 + lg * 4 + i;
#pragma unroll
      for (int n = 0; n < NF; ++n) {
        const int col = tn0 + wn * WN + n * 16 + lr;
        float v = acc[m][n][i];
        if (EPI == 1) v = fmaxf(v + bias[col], 0.f);
        if (EPI == 2) v = v + bias[col] + res[(size_t)row * N + col];
        if (EPI == 2) {
          ((float*)Cout)[(size_t)row * N + col] = v;
        } else if (EPI == 3) {
          if (col >= 2048) {
            const int hd = col - 2048;  // h*64 + d
            const size_t vidx =
                ((size_t)((row >> 11) * 16 + (hd >> 6)) * 64 + (hd & 63)) * TT + (row & (TT - 1));
            vt[vidx] = (bf16_t)v;
          } else {
            ((bf16_t*)Cout)[(size_t)row * N + col] = (bf16_t)v;
          }
        } else {
          ((bf16_t*)Cout)[(size_t)row * N + col] = (bf16_t)v;
        }
      }
    }
  }
}

// Flash attention, causal, D=64, T=2048. 4 waves/block, q-tile 64 rows (16/wave).
// KVBLK=128; K[s][d] and V^T[d][s] cooperatively staged (async split); per-wave P
// tile [16][136] with col^=(q>>3)<<4 (write banks free). LPT grid (heavy first),
// chunk-skip on diagonal, defer-max THR=8, l-reduce deferred to epilogue.
// Q pre-scaled by 2^-5 (exact in bf16).
__global__ __launch_bounds__(256, 3) void attn_fwd(const bf16_t* __restrict__ qkv,
                                                   const bf16_t* __restrict__ Vt,
                                                   bf16_t* __restrict__ O) {
  const int bh = blockIdx.x;
  const int bb = bh >> 4, hh = bh & 15;
  const int qt = 31 - (int)blockIdx.y;  // LPT: heaviest first
  const int qbase = qt * 64;
  const int tid = threadIdx.x;
  const int wave = tid >> 6, lane = tid & 63;
  const int lr = lane & 15, lg = lane >> 4;
  const bf16_t* Qp = qkv + (size_t)bb * TT * 3072 + hh * 64;
  const bf16_t* Kp = Qp + 1024;
  const bf16_t* Vh = Vt + (size_t)bh * 64 * TT;

  constexpr int KLP = 72;   // K tile [128 s][72]
  constexpr int VLP = 136;  // V^T tile [64 d][136]
  constexpr int PLP = 136;  // P tile [16 q][136] per wave
  __shared__ alignas(16) bf16_t Klds[128 * KLP];
  __shared__ alignas(16) bf16_t Vlds[64 * VLP];
  __shared__ alignas(16) bf16_t PlS[4][16 * PLP];
  bf16_t* Pw = PlS[wave];

  // staging geometry (per wave: K 4x8 rows of 128B, V 4x4 rows of 256B)
  const int ksr = wave * 32 + (lane >> 3);
  const int ksc = (lane & 7) * 8;
  const int vsr = wave * 16 + (lane >> 4);
  const int vsc = (lane & 15) * 8;

  const int qrow = qbase + wave * 16;
  bf16x8 qf0, qf1;
  {
    const bf16x8 a = *(const bf16x8*)(Qp + (size_t)(qrow + lr) * 3072 + lg * 8);
    const bf16x8 b = *(const bf16x8*)(Qp + (size_t)(qrow + lr) * 3072 + 32 + lg * 8);
#pragma unroll
    for (int j = 0; j < 8; ++j) {
      qf0[j] = (bf16_t)((float)a[j] * 0.03125f);
      qf1[j] = (bf16_t)((float)b[j] * 0.03125f);
    }
  }

  f32x4 oacc[4] = {};
  float m_r[4], l_r[4];
#pragma unroll
  for (int i = 0; i < 4; ++i) { m_r[i] = -1e38f; l_r[i] = 0.f; }

  bf16x8 kpre[4], vpre[4];
  // prologue: stage tile 0
#pragma unroll
  for (int i = 0; i < 4; ++i) {
    kpre[i] = *(const bf16x8*)(Kp + (size_t)(ksr + i * 8) * 3072 + ksc);
    vpre[i] = *(const bf16x8*)(Vh + (size_t)(vsr + i * 4) * TT + vsc);
  }
#pragma unroll
  for (int i = 0; i < 4; ++i) {
    *(bf16x8*)&Klds[(ksr + i * 8) * KLP + ksc] = kpre[i];
    *(bf16x8*)&Vlds[(vsr + i * 4) * VLP + vsc] = vpre[i];
  }
  __syncthreads();

  const int nt = (qt >> 1) + 1;
  for (int t = 0; t < nt; ++t) {
    const int s0 = t * 128;
    // issue next-tile loads (stay in flight across this iteration)
    const int sn = (t + 1 < nt) ? s0 + 128 : s0;
#pragma unroll
    for (int i = 0; i < 4; ++i) {
      kpre[i] = *(const bf16x8*)(Kp + (size_t)(sn + ksr + i * 8) * 3072 + ksc);
      vpre[i] = *(const bf16x8*)(Vh + (size_t)(vsr + i * 4) * TT + sn + vsc);
    }

    const int u = (qrow - s0) >> 4;       // # fully-unmasked 16-chunks (wave-uniform)
    const int cmc = min(u | 1, 7);        // last computed chunk (odd, <=7)

    // ---- QK^T over up to 128 s ----
    float P[8][4];
    __builtin_amdgcn_s_setprio(1);
#pragma unroll
    for (int ct = 0; ct < 8; ++ct) {
      if (ct <= cmc) {
        const bf16x8 kf0 = *(const bf16x8*)&Klds[(ct * 16 + lr) * KLP + lg * 8];
        const bf16x8 kf1 = *(const bf16x8*)&Klds[(ct * 16 + lr) * KLP + 32 + lg * 8];
        f32x4 z = {};
        z = __builtin_amdgcn_mfma_f32_16x16x32_bf16(qf0, kf0, z, 0, 0, 0);
        z = __builtin_amdgcn_mfma_f32_16x16x32_bf16(qf1, kf1, z, 0, 0, 0);
        if (ct >= u) {
          const int sg = s0 + ct * 16 + lr;
#pragma unroll
          for (int i = 0; i < 4; ++i)
            P[ct][i] = (sg > qrow + lg * 4 + i) ? -1e30f : z[i];
        } else {
#pragma unroll
          for (int i = 0; i < 4; ++i) P[ct][i] = z[i];
        }
      } else {
#pragma unroll
        for (int i = 0; i < 4; ++i) P[ct][i] = -1e30f;
      }
    }
    __builtin_amdgcn_s_setprio(0);

    // ---- local max + defer-max check (no shuffle on deferred path) ----
    float lmax[4];
#pragma unroll
    for (int i = 0; i < 4; ++i) {
      float m0 = fmaxf(fmaxf(P[0][i], P[1][i]), fmaxf(P[2][i], P[3][i]));
      float m1 = fmaxf(fmaxf(P[4][i], P[5][i]), fmaxf(P[6][i], P[7][i]));
      lmax[i] = fmaxf(m0, m1);
    }
    const bool ok = (lmax[0] <= m_r[0] + 8.f) && (lmax[1] <= m_r[1] + 8.f) &&
                    (lmax[2] <= m_r[2] + 8.f) && (lmax[3] <= m_r[3] + 8.f);
    if (!__all(ok)) {
      float rm[4] = {lmax[0], lmax[1], lmax[2], lmax[3]};
#pragma unroll
      for (int off = 1; off < 16; off <<= 1)
#pragma unroll
        for (int i = 0; i < 4; ++i) rm[i] = fmaxf(rm[i], __shfl_xor(rm[i], off));
#pragma unroll
      for (int i = 0; i < 4; ++i) {
        const float mn = fmaxf(m_r[i], rm[i]);
        const float alpha = __expf(m_r[i] - mn);
        m_r[i] = mn;
        l_r[i] *= alpha;
#pragma unroll
        for (int db = 0; db < 4; ++db) oacc[db][i] *= alpha;
      }
    }

    // ---- exp + per-lane partial l (cross-lane l-reduce deferred to epilogue) ----
#pragma unroll
    for (int i = 0; i < 4; ++i) {
      float ls = 0.f;
#pragma unroll
      for (int ct = 0; ct < 8; ++ct) {
        const float p = __expf(P[ct][i] - m_r[i]);
        P[ct][i] = p;
        ls += p;
      }
      l_r[i] += ls;
    }

    // ---- P -> LDS (padded + q-swizzled cols; conflict-free writes) ----
#pragma unroll
    for (int ct = 0; ct < 8; ++ct) {
      if (ct <= cmc) {
#pragma unroll
        for (int i = 0; i < 4; ++i) {
          const int q = lg * 4 + i;
          const int col = (ct * 16 + lr) ^ ((lg >> 1) << 4);
          Pw[q * PLP + col] = (bf16_t)P[ct][i];
        }
      }
    }
    asm volatile("s_waitcnt lgkmcnt(0)" ::: "memory");
    __builtin_amdgcn_sched_barrier(0);

    // ---- PV (kc clipped to computed chunks) ----
    const int kcm = cmc >> 1;
    __builtin_amdgcn_s_setprio(1);
#pragma unroll
    for (int kc = 0; kc < 4; ++kc) {
      if (kc <= kcm) {
        const bf16x8 pf =
            *(const bf16x8*)&Pw[lr * PLP + ((kc * 32 + lg * 8) ^ ((lr >> 3) << 4))];
#pragma unroll
        for (int db = 0; db < 4; ++db) {
          const bf16x8 vf = *(const bf16x8*)&Vlds[(db * 16 + lr) * VLP + kc * 32 + lg * 8];
          oacc[db] = __builtin_amdgcn_mfma_f32_16x16x32_bf16(pf, vf, oacc[db], 0, 0, 0);
        }
      }
    }
    __builtin_amdgcn_s_setprio(0);

    // ---- publish next tile ----
    if (t + 1 < nt) {
      __syncthreads();
#pragma unroll
      for (int i = 0; i < 4; ++i) {
        *(bf16x8*)&Klds[(ksr + i * 8) * KLP + ksc] = kpre[i];
        *(bf16x8*)&Vlds[(vsr + i * 4) * VLP + vsc] = vpre[i];
      }
      __syncthreads();
    }
  }

  // epilogue: reduce l across the 16 s-owner lanes, then store O = oacc/l
#pragma unroll
  for (int off = 1; off < 16; off <<= 1)
#pragma unroll
    for (int i = 0; i < 4; ++i) l_r[i] += __shfl_xor(l_r[i], off);

  bf16_t* Op = O + ((size_t)bb * TT + qrow) * CC + hh * 64;
#pragma unroll
  for (int i = 0; i < 4; ++i) {
    const float rl = 1.0f / l_r[i];
#pragma unroll
    for (int db = 0; db < 4; ++db)
      Op[(size_t)(lg * 4 + i) * CC + db * 16 + lr] = (bf16_t)(oacc[db][i] * rl);
  }
}

extern "C" void kernel_launch(void* const* d_in, const int* in_sizes, int n_in,
                              void* d_out, int out_size, void* d_ws, size_t ws_size,
                              hipStream_t stream) {
  const float* x      = (const float*)d_in[0];
  const float* wq     = (const float*)d_in[1];
  const float* wk     = (const float*)d_in[2];
  const float* wv     = (const float*)d_in[3];
  const float* w_proj = (const float*)d_in[4];
  const float* b_proj = (const float*)d_in[5];
  const float* w1     = (const float*)d_in[6];
  const float* b1     = (const float*)d_in[7];
  const float* w2     = (const float*)d_in[8];
  const float* b2     = (const float*)d_in[9];
  const float* ln1_g  = (const float*)d_in[10];
  const float* ln1_b  = (const float*)d_in[11];
  const float* ln2_g  = (const float*)d_in[12];
  const float* ln2_b  = (const float*)d_in[13];

  char* ws = (char*)d_ws;
  const size_t MB = 1024 * 1024;
  bf16_t* h1    = (bf16_t*)(ws + 0);         // 8 MB  [4096][1024]
  bf16_t* Bqkv  = (bf16_t*)(ws + 8 * MB);    // 6 MB  [3072][1024]
  bf16_t* Bproj = (bf16_t*)(ws + 14 * MB);   // 2 MB  [1024][1024]
  bf16_t* B1w   = (bf16_t*)(ws + 16 * MB);   // 8 MB  [4096][1024]
  bf16_t* B2w   = (bf16_t*)(ws + 24 * MB);   // 8 MB  [1024][4096]
  bf16_t* qkv   = (bf16_t*)(ws + 32 * MB);   // 24 MB [4096][3072] (V region unused)
  bf16_t* Obuf  = (bf16_t*)(ws + 56 * MB);   // 8 MB  [4096][1024]
  float*  res1  = (float*)(ws + 64 * MB);    // 16 MB [4096][1024], written AFTER attn
  bf16_t* Vt    = (bf16_t*)(ws + 64 * MB);   // 16 MB [32][64][2048], dead once attn done
  bf16_t* h2    = (bf16_t*)(ws + 80 * MB);   // 8 MB  [4096][1024]
  bf16_t* a1    = (bf16_t*)(ws + 32 * MB);   // 32 MB [4096][4096], reuses qkv+Obuf
  float*  outp  = (float*)d_out;

  dim3 blk(256);
  // weight prep: Bt[n][k] layouts
  transpose_cvt<<<dim3(32, 2, 16), blk, 0, stream>>>(wq, Bqkv, 1024, 64);
  transpose_cvt<<<dim3(32, 2, 16), blk, 0, stream>>>(wk, Bqkv + 1024 * 1024, 1024, 64);
  transpose_cvt<<<dim3(32, 2, 16), blk, 0, stream>>>(wv, Bqkv + 2 * 1024 * 1024, 1024, 64);
  transpose_cvt<<<dim3(32, 32, 1), blk, 0, stream>>>(w_proj, Bproj, 1024, 1024);
  transpose_cvt<<<dim3(32, 128, 1), blk, 0, stream>>>(w1, B1w, 1024, 4096);
  transpose_cvt<<<dim3(128, 32, 1), blk, 0, stream>>>(w2, B2w, 4096, 1024);

  ln_f32_bf16<<<dim3(4096), blk, 0, stream>>>(x, ln1_g, ln1_b, h1);
  gemm_bt<3, 128><<<dim3(24, 32), blk, 0, stream>>>(h1, Bqkv, qkv, nullptr, nullptr, Vt,
                                                    4096, 3072, 1024);
  attn_fwd<<<dim3(32, 32), blk, 0, stream>>>(qkv, Vt, Obuf);
  gemm_bt<2, 64><<<dim3(16, 32), blk, 0, stream>>>(Obuf, Bproj, res1, b_proj, x, nullptr,
                                                   4096, 1024, 1024);
  ln_f32_bf16<<<dim3(4096), blk, 0, stream>>>(res1, ln2_g, ln2_b, h2);
  gemm_bt<1, 128><<<dim3(32, 32), blk, 0, stream>>>(h2, B1w, a1, b1, nullptr, nullptr,
                                                    4096, 4096, 1024);
  gemm_bt<2, 64><<<dim3(16, 32), blk, 0, stream>>>(a1, B2w, outp, b2, res1, nullptr,
                                                   4096, 1024, 4096);
}

// Round 9
// 256.565 us; speedup vs baseline: 2.0867x; 1.0508x over previous
//
#include <hip/hip_runtime.h>
#include <hip/hip_bf16.h>
#include <stdint.h>

typedef __bf16 bf16_t;
typedef __bf16 bf16x8 __attribute__((ext_vector_type(8)));
typedef __bf16 bf16x4 __attribute__((ext_vector_type(4)));
typedef float f32x4 __attribute__((ext_vector_type(4)));

static constexpr int TT = 2048, CC = 1024;

__device__ __forceinline__ void gld_lds16(const void* g, void* l) {
  __builtin_amdgcn_global_load_lds((const __attribute__((address_space(1))) void*)g,
                                   (__attribute__((address_space(3))) void*)l, 16, 0, 0);
}

// out[n][k] = (bf16) in[k][n]; per-batch stride K*N both sides
__global__ __launch_bounds__(256) void transpose_cvt(const float* __restrict__ in,
                                                     bf16_t* __restrict__ out,
                                                     int K, int N) {
  __shared__ float t[32][33];
  const int k0 = blockIdx.x * 32, n0 = blockIdx.y * 32;
  const size_t boff = (size_t)blockIdx.z * K * N;
  in += boff;
  out += boff;
  const int tx = threadIdx.x & 31, ty = threadIdx.x >> 5;
#pragma unroll
  for (int j = 0; j < 4; ++j)
    t[ty + j * 8][tx] = in[(size_t)(k0 + ty + j * 8) * N + n0 + tx];
  __syncthreads();
#pragma unroll
  for (int j = 0; j < 4; ++j)
    out[(size_t)(n0 + ty + j * 8) * K + k0 + tx] = (bf16_t)t[tx][ty + j * 8];
}

// LayerNorm over C=1024, one block (256 thr) per row, bf16 out
__global__ __launch_bounds__(256) void ln_f32_bf16(const float* __restrict__ x,
                                                   const float* __restrict__ g,
                                                   const float* __restrict__ b,
                                                   bf16_t* __restrict__ out) {
  const int row = blockIdx.x;
  const int tid = threadIdx.x;
  const float4 v = ((const float4*)(x + (size_t)row * CC))[tid];
  float s = v.x + v.y + v.z + v.w;
  float q = v.x * v.x + v.y * v.y + v.z * v.z + v.w * v.w;
#pragma unroll
  for (int off = 1; off < 64; off <<= 1) {
    s += __shfl_xor(s, off);
    q += __shfl_xor(q, off);
  }
  __shared__ float red[8];
  const int wave = tid >> 6, lane = tid & 63;
  if (lane == 0) { red[wave] = s; red[4 + wave] = q; }
  __syncthreads();
  s = red[0] + red[1] + red[2] + red[3];
  q = red[4] + red[5] + red[6] + red[7];
  const float mu = s * (1.0f / CC);
  float var = q * (1.0f / CC) - mu * mu;
  var = fmaxf(var, 0.f);
  const float rstd = rsqrtf(var + 1e-5f);
  const float4 gv = ((const float4*)g)[tid];
  const float4 bv = ((const float4*)b)[tid];
  bf16x4 o;
  o[0] = (bf16_t)((v.x - mu) * rstd * gv.x + bv.x);
  o[1] = (bf16_t)((v.y - mu) * rstd * gv.y + bv.y);
  o[2] = (bf16_t)((v.z - mu) * rstd * gv.z + bv.z);
  o[3] = (bf16_t)((v.w - mu) * rstd * gv.w + bv.w);
  *(bf16x4*)(out + (size_t)row * CC + tid * 4) = o;
}

// C = A[M,K] @ Bt[N,K]^T ; A,Bt bf16 row-major. Tile 128 x BN, BK=64, 4 waves (2x2).
// 2-phase double-buffered K-loop (T3 minimum): STAGE(t+1) issued right after the
// barrier, compute(t) overlaps the stage latency, one vmcnt(0)+s_barrier per tile.
// LDS rows 64 elems (128B), chunk XOR-swizzle c^=(row&7) via inverse-swizzled global
// source + swizzled fragment reads (rule #21; HW-verified conflict-free in R7).
// EPI: 0 = bf16 store; 1 = bf16 relu(acc+bias); 2 = f32 acc+bias+res
// EPI: 3 = bf16 store, cols >= 2048 transposed to vt[bh][d][T] (QKV fused V-transpose)
template <int EPI, int BN>
__global__ __launch_bounds__(256) void gemm_bt(const bf16_t* __restrict__ A,
                                               const bf16_t* __restrict__ Bt,
                                               void* __restrict__ Cout,
                                               const float* __restrict__ bias,
                                               const float* __restrict__ res,
                                               bf16_t* __restrict__ vt,
                                               int M, int N, int K) {
  constexpr int WN = BN / 2;   // wave n-extent
  constexpr int NF = BN / 32;  // n-frags per wave
  constexpr int NB = BN / 32;  // B staging instrs per wave
  __shared__ alignas(16) bf16_t As[2][128 * 64];
  __shared__ alignas(16) bf16_t Bs[2][BN * 64];
  const int tid = threadIdx.x;
  const int wave = tid >> 6, lane = tid & 63;
  const int lr = lane & 15, lg = lane >> 4;
  const int wm = wave >> 1, wn = wave & 1;
  const int tm0 = blockIdx.y * 128, tn0 = blockIdx.x * BN;

  // staging: lane covers 16B chunk of row sr within a 32-row group;
  // global source chunk is (lane&7)^sr so LDS[r][c] holds global chunk c^(r&7)
  const int sr = lane >> 3;          // 0..7
  const int scs = (lane & 7) ^ sr;   // swizzled source chunk
  const bf16_t* Ag[4];
#pragma unroll
  for (int i = 0; i < 4; ++i)
    Ag[i] = A + (size_t)(tm0 + i * 32 + wave * 8 + sr) * K + scs * 8;
  const bf16_t* Bg[NB];
#pragma unroll
  for (int i = 0; i < NB; ++i)
    Bg[i] = Bt + (size_t)(tn0 + i * 32 + wave * 8 + sr) * K + scs * 8;

  auto STAGE = [&](int k0, bf16_t* Ad, bf16_t* Bd) {
#pragma unroll
    for (int i = 0; i < 4; ++i)
      gld_lds16(Ag[i] + k0, Ad + (i * 32 + wave * 8) * 64);
#pragma unroll
    for (int i = 0; i < NB; ++i)
      gld_lds16(Bg[i] + k0, Bd + (i * 32 + wave * 8) * 64);
  };

  f32x4 acc[4][NF] = {};
  const int NT = K >> 6;

  // prologue: stage tile 0
  STAGE(0, As[0], Bs[0]);
  asm volatile("s_waitcnt vmcnt(0)" ::: "memory");
  __builtin_amdgcn_s_barrier();

  for (int t = 0; t < NT; ++t) {
    const int cur = t & 1;
    bf16_t* Ac = As[cur];
    bf16_t* Bc = Bs[cur];
    if (t + 1 < NT) STAGE((t + 1) << 6, As[cur ^ 1], Bs[cur ^ 1]);

    bf16x8 af[2][4], bfr[2][NF];
#pragma unroll
    for (int kk = 0; kk < 2; ++kk) {
      const int ch = ((kk * 4 + lg) ^ (lr & 7)) * 8;
#pragma unroll
      for (int m = 0; m < 4; ++m)
        af[kk][m] = *(const bf16x8*)&Ac[(wm * 64 + m * 16 + lr) * 64 + ch];
#pragma unroll
      for (int n = 0; n < NF; ++n)
        bfr[kk][n] = *(const bf16x8*)&Bc[(wn * WN + n * 16 + lr) * 64 + ch];
    }
    asm volatile("s_waitcnt lgkmcnt(0)" ::: "memory");
    __builtin_amdgcn_sched_barrier(0);
    __builtin_amdgcn_s_setprio(1);
#pragma unroll
    for (int kk = 0; kk < 2; ++kk)
#pragma unroll
      for (int m = 0; m < 4; ++m)
#pragma unroll
        for (int n = 0; n < NF; ++n)
          acc[m][n] =
              __builtin_amdgcn_mfma_f32_16x16x32_bf16(af[kk][m], bfr[kk][n], acc[m][n], 0, 0, 0);
    __builtin_amdgcn_s_setprio(0);
    // wait for STAGE(t+1) (issued one compute-phase ago) to land, then publish
    asm volatile("s_waitcnt vmcnt(0)" ::: "memory");
    __builtin_amdgcn_sched_barrier(0);
    __builtin_amdgcn_s_barrier();
  }

#pragma unroll
  for (int m = 0; m < 4; ++m) {
#pragma unroll
    for (int i = 0; i < 4; ++i) {
      const int row = tm0 + wm * 64 + m * 16 + lg * 4 + i;
#pragma unroll
      for (int n = 0; n < NF; ++n) {
        const int col = tn0 + wn * WN + n * 16 + lr;
        float v = acc[m][n][i];
        if (EPI == 1) v = fmaxf(v + bias[col], 0.f);
        if (EPI == 2) v = v + bias[col] + res[(size_t)row * N + col];
        if (EPI == 2) {
          ((float*)Cout)[(size_t)row * N + col] = v;
        } else if (EPI == 3) {
          if (col >= 2048) {
            const int hd = col - 2048;  // h*64 + d
            const size_t vidx =
                ((size_t)((row >> 11) * 16 + (hd >> 6)) * 64 + (hd & 63)) * TT + (row & (TT - 1));
            vt[vidx] = (bf16_t)v;
          } else {
            ((bf16_t*)Cout)[(size_t)row * N + col] = (bf16_t)v;
          }
        } else {
          ((bf16_t*)Cout)[(size_t)row * N + col] = (bf16_t)v;
        }
      }
    }
  }
}

// Flash attention, causal, D=64, T=2048. 4 waves/block, q-tile 64 rows (16/wave).
// KVBLK=128; K[s][d] and V^T[d][s] cooperatively staged (async split); per-wave P
// tile [16][136] with col^=(q>>3)<<4 (write banks free). LPT grid (heavy first),
// chunk-skip on diagonal, defer-max THR=8, l-reduce deferred to epilogue.
// Q pre-scaled by 2^-5 (exact in bf16).
__global__ __launch_bounds__(256, 3) void attn_fwd(const bf16_t* __restrict__ qkv,
                                                   const bf16_t* __restrict__ Vt,
                                                   bf16_t* __restrict__ O) {
  const int bh = blockIdx.x;
  const int bb = bh >> 4, hh = bh & 15;
  const int qt = 31 - (int)blockIdx.y;  // LPT: heaviest first
  const int qbase = qt * 64;
  const int tid = threadIdx.x;
  const int wave = tid >> 6, lane = tid & 63;
  const int lr = lane & 15, lg = lane >> 4;
  const bf16_t* Qp = qkv + (size_t)bb * TT * 3072 + hh * 64;
  const bf16_t* Kp = Qp + 1024;
  const bf16_t* Vh = Vt + (size_t)bh * 64 * TT;

  constexpr int KLP = 72;   // K tile [128 s][72]
  constexpr int VLP = 136;  // V^T tile [64 d][136]
  constexpr int PLP = 136;  // P tile [16 q][136] per wave
  __shared__ alignas(16) bf16_t Klds[128 * KLP];
  __shared__ alignas(16) bf16_t Vlds[64 * VLP];
  __shared__ alignas(16) bf16_t PlS[4][16 * PLP];
  bf16_t* Pw = PlS[wave];

  // staging geometry (per wave: K 4x8 rows of 128B, V 4x4 rows of 256B)
  const int ksr = wave * 32 + (lane >> 3);
  const int ksc = (lane & 7) * 8;
  const int vsr = wave * 16 + (lane >> 4);
  const int vsc = (lane & 15) * 8;

  const int qrow = qbase + wave * 16;
  bf16x8 qf0, qf1;
  {
    const bf16x8 a = *(const bf16x8*)(Qp + (size_t)(qrow + lr) * 3072 + lg * 8);
    const bf16x8 b = *(const bf16x8*)(Qp + (size_t)(qrow + lr) * 3072 + 32 + lg * 8);
#pragma unroll
    for (int j = 0; j < 8; ++j) {
      qf0[j] = (bf16_t)((float)a[j] * 0.03125f);
      qf1[j] = (bf16_t)((float)b[j] * 0.03125f);
    }
  }

  f32x4 oacc[4] = {};
  float m_r[4], l_r[4];
#pragma unroll
  for (int i = 0; i < 4; ++i) { m_r[i] = -1e38f; l_r[i] = 0.f; }

  bf16x8 kpre[4], vpre[4];
  // prologue: stage tile 0
#pragma unroll
  for (int i = 0; i < 4; ++i) {
    kpre[i] = *(const bf16x8*)(Kp + (size_t)(ksr + i * 8) * 3072 + ksc);
    vpre[i] = *(const bf16x8*)(Vh + (size_t)(vsr + i * 4) * TT + vsc);
  }
#pragma unroll
  for (int i = 0; i < 4; ++i) {
    *(bf16x8*)&Klds[(ksr + i * 8) * KLP + ksc] = kpre[i];
    *(bf16x8*)&Vlds[(vsr + i * 4) * VLP + vsc] = vpre[i];
  }
  __syncthreads();

  const int nt = (qt >> 1) + 1;
  for (int t = 0; t < nt; ++t) {
    const int s0 = t * 128;
    // issue next-tile loads (stay in flight across this iteration)
    const int sn = (t + 1 < nt) ? s0 + 128 : s0;
#pragma unroll
    for (int i = 0; i < 4; ++i) {
      kpre[i] = *(const bf16x8*)(Kp + (size_t)(sn + ksr + i * 8) * 3072 + ksc);
      vpre[i] = *(const bf16x8*)(Vh + (size_t)(vsr + i * 4) * TT + sn + vsc);
    }

    const int u = (qrow - s0) >> 4;       // # fully-unmasked 16-chunks (wave-uniform)
    const int cmc = min(u | 1, 7);        // last computed chunk (odd, <=7)

    // ---- QK^T over up to 128 s ----
    float P[8][4];
    __builtin_amdgcn_s_setprio(1);
#pragma unroll
    for (int ct = 0; ct < 8; ++ct) {
      if (ct <= cmc) {
        const bf16x8 kf0 = *(const bf16x8*)&Klds[(ct * 16 + lr) * KLP + lg * 8];
        const bf16x8 kf1 = *(const bf16x8*)&Klds[(ct * 16 + lr) * KLP + 32 + lg * 8];
        f32x4 z = {};
        z = __builtin_amdgcn_mfma_f32_16x16x32_bf16(qf0, kf0, z, 0, 0, 0);
        z = __builtin_amdgcn_mfma_f32_16x16x32_bf16(qf1, kf1, z, 0, 0, 0);
        if (ct >= u) {
          const int sg = s0 + ct * 16 + lr;
#pragma unroll
          for (int i = 0; i < 4; ++i)
            P[ct][i] = (sg > qrow + lg * 4 + i) ? -1e30f : z[i];
        } else {
#pragma unroll
          for (int i = 0; i < 4; ++i) P[ct][i] = z[i];
        }
      } else {
#pragma unroll
        for (int i = 0; i < 4; ++i) P[ct][i] = -1e30f;
      }
    }
    __builtin_amdgcn_s_setprio(0);

    // ---- local max + defer-max check (no shuffle on deferred path) ----
    float lmax[4];
#pragma unroll
    for (int i = 0; i < 4; ++i) {
      float m0 = fmaxf(fmaxf(P[0][i], P[1][i]), fmaxf(P[2][i], P[3][i]));
      float m1 = fmaxf(fmaxf(P[4][i], P[5][i]), fmaxf(P[6][i], P[7][i]));
      lmax[i] = fmaxf(m0, m1);
    }
    const bool ok = (lmax[0] <= m_r[0] + 8.f) && (lmax[1] <= m_r[1] + 8.f) &&
                    (lmax[2] <= m_r[2] + 8.f) && (lmax[3] <= m_r[3] + 8.f);
    if (!__all(ok)) {
      float rm[4] = {lmax[0], lmax[1], lmax[2], lmax[3]};
#pragma unroll
      for (int off = 1; off < 16; off <<= 1)
#pragma unroll
        for (int i = 0; i < 4; ++i) rm[i] = fmaxf(rm[i], __shfl_xor(rm[i], off));
#pragma unroll
      for (int i = 0; i < 4; ++i) {
        const float mn = fmaxf(m_r[i], rm[i]);
        const float alpha = __expf(m_r[i] - mn);
        m_r[i] = mn;
        l_r[i] *= alpha;
#pragma unroll
        for (int db = 0; db < 4; ++db) oacc[db][i] *= alpha;
      }
    }

    // ---- exp + per-lane partial l (cross-lane l-reduce deferred to epilogue) ----
#pragma unroll
    for (int i = 0; i < 4; ++i) {
      float ls = 0.f;
#pragma unroll
      for (int ct = 0; ct < 8; ++ct) {
        const float p = __expf(P[ct][i] - m_r[i]);
        P[ct][i] = p;
        ls += p;
      }
      l_r[i] += ls;
    }

    // ---- P -> LDS (padded + q-swizzled cols; conflict-free writes) ----
#pragma unroll
    for (int ct = 0; ct < 8; ++ct) {
      if (ct <= cmc) {
#pragma unroll
        for (int i = 0; i < 4; ++i) {
          const int q = lg * 4 + i;
          const int col = (ct * 16 + lr) ^ ((lg >> 1) << 4);
          Pw[q * PLP + col] = (bf16_t)P[ct][i];
        }
      }
    }
    asm volatile("s_waitcnt lgkmcnt(0)" ::: "memory");
    __builtin_amdgcn_sched_barrier(0);

    // ---- PV (kc clipped to computed chunks) ----
    const int kcm = cmc >> 1;
    __builtin_amdgcn_s_setprio(1);
#pragma unroll
    for (int kc = 0; kc < 4; ++kc) {
      if (kc <= kcm) {
        const bf16x8 pf =
            *(const bf16x8*)&Pw[lr * PLP + ((kc * 32 + lg * 8) ^ ((lr >> 3) << 4))];
#pragma unroll
        for (int db = 0; db < 4; ++db) {
          const bf16x8 vf = *(const bf16x8*)&Vlds[(db * 16 + lr) * VLP + kc * 32 + lg * 8];
          oacc[db] = __builtin_amdgcn_mfma_f32_16x16x32_bf16(pf, vf, oacc[db], 0, 0, 0);
        }
      }
    }
    __builtin_amdgcn_s_setprio(0);

    // ---- publish next tile ----
    if (t + 1 < nt) {
      __syncthreads();
#pragma unroll
      for (int i = 0; i < 4; ++i) {
        *(bf16x8*)&Klds[(ksr + i * 8) * KLP + ksc] = kpre[i];
        *(bf16x8*)&Vlds[(vsr + i * 4) * VLP + vsc] = vpre[i];
      }
      __syncthreads();
    }
  }

  // epilogue: reduce l across the 16 s-owner lanes, then store O = oacc/l
#pragma unroll
  for (int off = 1; off < 16; off <<= 1)
#pragma unroll
    for (int i = 0; i < 4; ++i) l_r[i] += __shfl_xor(l_r[i], off);

  bf16_t* Op = O + ((size_t)bb * TT + qrow) * CC + hh * 64;
#pragma unroll
  for (int i = 0; i < 4; ++i) {
    const float rl = 1.0f / l_r[i];
#pragma unroll
    for (int db = 0; db < 4; ++db)
      Op[(size_t)(lg * 4 + i) * CC + db * 16 + lr] = (bf16_t)(oacc[db][i] * rl);
  }
}

extern "C" void kernel_launch(void* const* d_in, const int* in_sizes, int n_in,
                              void* d_out, int out_size, void* d_ws, size_t ws_size,
                              hipStream_t stream) {
  const float* x      = (const float*)d_in[0];
  const float* wq     = (const float*)d_in[1];
  const float* wk     = (const float*)d_in[2];
  const float* wv     = (const float*)d_in[3];
  const float* w_proj = (const float*)d_in[4];
  const float* b_proj = (const float*)d_in[5];
  const float* w1     = (const float*)d_in[6];
  const float* b1     = (const float*)d_in[7];
  const float* w2     = (const float*)d_in[8];
  const float* b2     = (const float*)d_in[9];
  const float* ln1_g  = (const float*)d_in[10];
  const float* ln1_b  = (const float*)d_in[11];
  const float* ln2_g  = (const float*)d_in[12];
  const float* ln2_b  = (const float*)d_in[13];

  char* ws = (char*)d_ws;
  const size_t MB = 1024 * 1024;
  bf16_t* h1    = (bf16_t*)(ws + 0);         // 8 MB  [4096][1024]
  bf16_t* Bqkv  = (bf16_t*)(ws + 8 * MB);    // 6 MB  [3072][1024]
  bf16_t* Bproj = (bf16_t*)(ws + 14 * MB);   // 2 MB  [1024][1024]
  bf16_t* B1w   = (bf16_t*)(ws + 16 * MB);   // 8 MB  [4096][1024]
  bf16_t* B2w   = (bf16_t*)(ws + 24 * MB);   // 8 MB  [1024][4096]
  bf16_t* qkv   = (bf16_t*)(ws + 32 * MB);   // 24 MB [4096][3072] (V region unused)
  bf16_t* Obuf  = (bf16_t*)(ws + 56 * MB);   // 8 MB  [4096][1024]
  float*  res1  = (float*)(ws + 64 * MB);    // 16 MB [4096][1024], written AFTER attn
  bf16_t* Vt    = (bf16_t*)(ws + 64 * MB);   // 16 MB [32][64][2048], dead once attn done
  bf16_t* h2    = (bf16_t*)(ws + 80 * MB);   // 8 MB  [4096][1024]
  bf16_t* a1    = (bf16_t*)(ws + 32 * MB);   // 32 MB [4096][4096], reuses qkv+Obuf
  float*  outp  = (float*)d_out;

  dim3 blk(256);
  // weight prep: Bt[n][k] layouts
  transpose_cvt<<<dim3(32, 2, 16), blk, 0, stream>>>(wq, Bqkv, 1024, 64);
  transpose_cvt<<<dim3(32, 2, 16), blk, 0, stream>>>(wk, Bqkv + 1024 * 1024, 1024, 64);
  transpose_cvt<<<dim3(32, 2, 16), blk, 0, stream>>>(wv, Bqkv + 2 * 1024 * 1024, 1024, 64);
  transpose_cvt<<<dim3(32, 32, 1), blk, 0, stream>>>(w_proj, Bproj, 1024, 1024);
  transpose_cvt<<<dim3(32, 128, 1), blk, 0, stream>>>(w1, B1w, 1024, 4096);
  transpose_cvt<<<dim3(128, 32, 1), blk, 0, stream>>>(w2, B2w, 4096, 1024);

  ln_f32_bf16<<<dim3(4096), blk, 0, stream>>>(x, ln1_g, ln1_b, h1);
  gemm_bt<3, 128><<<dim3(24, 32), blk, 0, stream>>>(h1, Bqkv, qkv, nullptr, nullptr, Vt,
                                                    4096, 3072, 1024);
  attn_fwd<<<dim3(32, 32), blk, 0, stream>>>(qkv, Vt, Obuf);
  gemm_bt<2, 64><<<dim3(16, 32), blk, 0, stream>>>(Obuf, Bproj, res1, b_proj, x, nullptr,
                                                   4096, 1024, 1024);
  ln_f32_bf16<<<dim3(4096), blk, 0, stream>>>(res1, ln2_g, ln2_b, h2);
  gemm_bt<1, 128><<<dim3(32, 32), blk, 0, stream>>>(h2, B1w, a1, b1, nullptr, nullptr,
                                                    4096, 4096, 1024);
  gemm_bt<2, 64><<<dim3(16, 32), blk, 0, stream>>>(a1, B2w, outp, b2, res1, nullptr,
                                                   4096, 1024, 4096);
}